// Round 3
// baseline (554.939 us; speedup 1.0000x reference)
//
#include <hip/hip_runtime.h>
#include <hip/hip_bf16.h>

#define S_LEN 2048
#define HID 2048
#define NB 2
#define NH 16
#define NKV 8
#define DH 128
#define RQ 6
#define KG 2048
#define SCALING 0.08838834764831845f

typedef __attribute__((ext_vector_type(8))) short s16x8;
typedef __attribute__((ext_vector_type(4))) float f32x4;

__device__ __forceinline__ float bf2f(ushort u) {
    union { unsigned int i; float f; } v; v.i = ((unsigned int)u) << 16; return v.f;
}
__device__ __forceinline__ ushort f2bf(float f) {
    __hip_bfloat16 h = __float2bfloat16(f);
    return *reinterpret_cast<ushort*>(&h);
}
__device__ __forceinline__ void g2lds16(const void* g, void* l) {
    __builtin_amdgcn_global_load_lds((const __attribute__((address_space(1))) void*)g,
                                     (__attribute__((address_space(3))) void*)l, 16, 0, 0);
}

// ---------------- fp32 -> bf16 convert (vector) ----------------
__global__ void k_cvt_bf16(const float* __restrict__ in, ushort* __restrict__ out, int n4) {
    int i = blockIdx.x * 256 + threadIdx.x;
    if (i >= n4) return;
    float4 v = ((const float4*)in)[i];
    ushort4 o;
    o.x = f2bf(v.x); o.y = f2bf(v.y); o.z = f2bf(v.z); o.w = f2bf(v.w);
    ((ushort4*)out)[i] = o;
}

// ---------------- weight transpose+convert: in [K=2048][Nin] f32 -> out [(rowOff+n)][2048] bf16 ----------------
__global__ void k_transpose_w(const float* __restrict__ in, ushort* __restrict__ out, int Nin, int rowOff) {
    __shared__ ushort tile[64][66];
    int k0 = blockIdx.x * 64, n0 = blockIdx.y * 64;
    int t = threadIdx.x;
#pragma unroll
    for (int i = 0; i < 16; ++i) {
        int f = t + i * 256; int r = f >> 6, c = f & 63;
        int nn = n0 + c;
        float v = (nn < Nin) ? in[(size_t)(k0 + r) * Nin + nn] : 0.f;
        tile[r][c] = f2bf(v);
    }
    __syncthreads();
#pragma unroll
    for (int i = 0; i < 16; ++i) {
        int f = t + i * 256; int nr = f >> 6, kc = f & 63;
        int nn = n0 + nr;
        if (nn < Nin) out[(size_t)(rowOff + nn) * KG + k0 + kc] = tile[kc][nr];
    }
}

// ---------------- generic bf16 GEMM: A[M][2048] @ Bt[N][2048]^T -> C[M][ldc], 128x128 tile ----------------
__device__ __forceinline__ void stc(float* p, float v) { *p = v; }
__device__ __forceinline__ void stc(ushort* p, float v) { *p = f2bf(v); }

template<typename OutT>
__global__ __launch_bounds__(256, 2) void k_gemm(const ushort* __restrict__ A,
                                                 const ushort* __restrict__ Bt,
                                                 OutT* __restrict__ C, int ldc) {
    __shared__ ushort lA[128 * 64];
    __shared__ ushort lB[128 * 64];
    const int tid = threadIdx.x;
    const int l = tid & 63, w = tid >> 6;
    const int gx = gridDim.x;
    int flat = blockIdx.y * gx + blockIdx.x;
    const int nwg = gx * gridDim.y;
    if ((nwg & 7) == 0) {
        int qq = nwg >> 3;
        flat = (flat & 7) * qq + (flat >> 3);
    }
    const int m0 = (flat % gx) * 128, n0 = (flat / gx) * 128;
    const int wm = w >> 1, wn = w & 1;
    f32x4 acc[4][4] = {};
    const int swz = 16 * ((tid & 7) ^ ((tid >> 3) & 7));
    const int rowbase = tid >> 3;

    for (int k0 = 0; k0 < KG; k0 += 64) {
#pragma unroll
        for (int i = 0; i < 4; ++i) {
            int row = rowbase + i * 32;
            const char* srcA = (const char*)A + (((size_t)(m0 + row) * KG + k0) * 2) + swz;
            g2lds16(srcA, (char*)lA + tid * 16 + i * 4096);
            const char* srcB = (const char*)Bt + (((size_t)(n0 + row) * KG + k0) * 2) + swz;
            g2lds16(srcB, (char*)lB + tid * 16 + i * 4096);
        }
        __syncthreads();
#pragma unroll
        for (int kk = 0; kk < 2; ++kk) {
            s16x8 af[4], bfr[4];
            const int kb = kk * 64 + (l >> 4) * 16;
#pragma unroll
            for (int mf = 0; mf < 4; ++mf) {
                int row = wm * 64 + mf * 16 + (l & 15);
                af[mf] = *(const s16x8*)((const char*)lA + row * 128 + (kb ^ ((row & 7) << 4)));
            }
#pragma unroll
            for (int nf = 0; nf < 4; ++nf) {
                int row = wn * 64 + nf * 16 + (l & 15);
                bfr[nf] = *(const s16x8*)((const char*)lB + row * 128 + (kb ^ ((row & 7) << 4)));
            }
#pragma unroll
            for (int mf = 0; mf < 4; ++mf)
#pragma unroll
                for (int nf = 0; nf < 4; ++nf)
                    acc[mf][nf] = __builtin_amdgcn_mfma_f32_16x16x32_bf16(af[mf], bfr[nf], acc[mf][nf], 0, 0, 0);
        }
        __syncthreads();
    }
#pragma unroll
    for (int mf = 0; mf < 4; ++mf)
#pragma unroll
        for (int r = 0; r < 4; ++r) {
            int row = m0 + wm * 64 + mf * 16 + (l >> 4) * 4 + r;
#pragma unroll
            for (int nf = 0; nf < 4; ++nf) {
                int col = n0 + wn * 64 + nf * 16 + (l & 15);
                stc(C + (size_t)row * ldc + col, acc[mf][nf][r]);
            }
        }
}

// ---------------- 256x256 counted-vmcnt pipelined GEMM (BK=32, 4-slot LDS ring) ----------------
// A[M][2048] @ Bt[N][2048]^T -> C[M][ldc] bf16. Grid: flat tiles (16 m x ntile n), 512 threads.
// Ring safety: stage at iter t targets slot (t+3)&3, whose reads ended at iter t-1 (barrier passed).
// End-of-iter vmcnt(8)+s_barrier => tile t+1 globally landed. Never drains to 0 in steady state.
__global__ __launch_bounds__(512, 2) void k_gemm256(const ushort* __restrict__ A,
                                                    const ushort* __restrict__ Bt,
                                                    ushort* __restrict__ C, int ldc) {
    __shared__ char sBuf[131072];        // 4 slots x (A 16KB + B 16KB)
    const int tid = threadIdx.x;
    const int l = tid & 63, wid = tid >> 6;
    const int wr = wid >> 2, wc = wid & 3;

    int flat = blockIdx.x;
    const int nwg = gridDim.x;
    if ((nwg & 7) == 0) {
        int qq = nwg >> 3;
        flat = (flat & 7) * qq + (flat >> 3);
    }
    const int m0 = (flat & 15) * 256;
    const int n0 = (flat >> 4) * 256;

    // read-side lane constant (pair-interleave swizzle over 128B LDS rows)
    const int lam = (l >> 1) & 7;
    const int qlog = (l & 1) * 4 + (l >> 4);
    const int laneK = lam * 128 + ((qlog ^ lam) * 16);

    // write-side (inverse swizzle applied to global source)
    const int rq = tid & 7;
    const int r3 = (tid >> 3) & 7;
    const int qlw = rq ^ r3;
    const int colb = (qlw & 3) * 16;
    const int tokoff = ((tid >> 3) << 1) + (qlw >> 2);
    const char* pA[2]; const char* pB[2];
#pragma unroll
    for (int i = 0; i < 2; ++i) {
        int tok = i * 128 + tokoff;
        pA[i] = (const char*)A + (size_t)(m0 + tok) * (KG * 2) + colb;
        pB[i] = (const char*)Bt + (size_t)(n0 + tok) * (KG * 2) + colb;
    }
    const int ldst = tid * 16;           // linear LDS dest offset for this thread

    f32x4 acc[8][4] = {};

    // prologue: stage tiles 0,1,2 into slots 0,1,2
#pragma unroll
    for (int p = 0; p < 3; ++p) {
        char* slot = sBuf + p * 32768;
#pragma unroll
        for (int i = 0; i < 2; ++i)
            g2lds16(pA[i] + p * 64, slot + i * 8192 + ldst);
#pragma unroll
        for (int i = 0; i < 2; ++i)
            g2lds16(pB[i] + p * 64, slot + 16384 + i * 8192 + ldst);
    }
    asm volatile("s_waitcnt vmcnt(8)" ::: "memory");
    __builtin_amdgcn_s_barrier();
    asm volatile("" ::: "memory");

    const int NT = KG / 32;              // 64
    for (int kt = 0; kt < NT; ++kt) {
        const int cur = kt & 3;
        // stage tile kt+3
        if (kt < NT - 3) {
            char* slot = sBuf + ((kt + 3) & 3) * 32768;
            size_t ko = (size_t)(kt + 3) * 64;
#pragma unroll
            for (int i = 0; i < 2; ++i)
                g2lds16(pA[i] + ko, slot + i * 8192 + ldst);
#pragma unroll
            for (int i = 0; i < 2; ++i)
                g2lds16(pB[i] + ko, slot + 16384 + i * 8192 + ldst);
        }
        // frag reads (compiler inserts lgkmcnt before MFMA uses)
        const char* aslot = sBuf + cur * 32768;
        s16x8 af[8], bfv[4];
#pragma unroll
        for (int mf = 0; mf < 8; ++mf)
            af[mf] = *(const s16x8*)(aslot + (wr * 128 + mf * 16) * 64 + laneK);
#pragma unroll
        for (int nf = 0; nf < 4; ++nf)
            bfv[nf] = *(const s16x8*)(aslot + 16384 + (wc * 64 + nf * 16) * 64 + laneK);

        __builtin_amdgcn_s_setprio(1);
#pragma unroll
        for (int mf = 0; mf < 8; ++mf)
#pragma unroll
            for (int nf = 0; nf < 4; ++nf)
                acc[mf][nf] = __builtin_amdgcn_mfma_f32_16x16x32_bf16(af[mf], bfv[nf], acc[mf][nf], 0, 0, 0);
        __builtin_amdgcn_s_setprio(0);

        if (kt < NT - 1) {
            if (kt <= NT - 4)      asm volatile("s_waitcnt vmcnt(8)" ::: "memory");
            else if (kt == NT - 3) asm volatile("s_waitcnt vmcnt(4)" ::: "memory");
            else                   asm volatile("s_waitcnt vmcnt(0)" ::: "memory");
            __builtin_amdgcn_s_barrier();
            asm volatile("" ::: "memory");
        }
    }

    // epilogue: C write
#pragma unroll
    for (int mf = 0; mf < 8; ++mf)
#pragma unroll
        for (int r = 0; r < 4; ++r) {
            int row = m0 + wr * 128 + mf * 16 + (l >> 4) * 4 + r;
#pragma unroll
            for (int nf = 0; nf < 4; ++nf) {
                int col = n0 + wc * 64 + nf * 16 + (l & 15);
                C[(size_t)row * ldc + col] = f2bf(acc[mf][nf][r]);
            }
        }
}

// ---------------- contract ranks + rope + scale for q (one Bq chunk of 4 heads) ----------------
__global__ void k_contract_q(const ushort* __restrict__ bq, const float* __restrict__ small,
                             const float* __restrict__ cosT, const float* __restrict__ sinT,
                             ushort* __restrict__ q, int chunk) {
    int srow = blockIdx.x;               // 0..4095 == b*2048 + s
    int b = srow >> 11, sl = srow & 2047;
    int t = threadIdx.x;
    int d2 = t & 63, hp = t >> 6;        // hp 0..3
    int h = chunk * 4 + hp;
    const ushort* bqr = bq + (size_t)srow * 3072 + hp * 768;
    const float* af = small + (size_t)srow * 640 + h * RQ;
    float x1 = 0.f, x2 = 0.f;
#pragma unroll
    for (int r = 0; r < RQ; ++r) {
        float a = af[r];
        x1 += a * bf2f(bqr[r * 128 + d2]);
        x2 += a * bf2f(bqr[r * 128 + 64 + d2]);
    }
    float c = cosT[sl * 64 + d2], s = sinT[sl * 64 + d2];
    float q1 = (x1 * c - x2 * s) * SCALING;
    float q2 = (x1 * s + x2 * c) * SCALING;
    size_t o = ((size_t)(b * NH + h) * S_LEN + sl) * DH + d2;
    q[o] = f2bf(q1);
    q[o + 64] = f2bf(q2);
}

// ---------------- contract ranks for k (rope) and v (write v^T) ----------------
__global__ void k_contract_kv(const float* __restrict__ small, const float* __restrict__ cosT,
                              const float* __restrict__ sinT, ushort* __restrict__ kk,
                              ushort* __restrict__ vT) {
    int srow = blockIdx.x;
    int b = srow >> 11, sl = srow & 2047;
    int t = threadIdx.x;                 // 512 threads
    int d2 = t & 63, g = t >> 6;         // g 0..7
    const float* row = small + (size_t)srow * 640;
    float k1 = 0.f, k2 = 0.f, v1 = 0.f, v2 = 0.f;
#pragma unroll
    for (int r = 0; r < 2; ++r) {
        float ak = row[96 + g * 2 + r];
        k1 += ak * row[128 + r * 128 + d2];
        k2 += ak * row[128 + r * 128 + 64 + d2];
        float av = row[112 + g * 2 + r];
        v1 += av * row[384 + r * 128 + d2];
        v2 += av * row[384 + r * 128 + 64 + d2];
    }
    float c = cosT[sl * 64 + d2], s = sinT[sl * 64 + d2];
    float kr1 = k1 * c - k2 * s, kr2 = k1 * s + k2 * c;
    size_t ko = ((size_t)(b * NKV + g) * S_LEN + sl) * DH + d2;
    kk[ko] = f2bf(kr1);
    kk[ko + 64] = f2bf(kr2);
    size_t vo = ((size_t)(b * NKV + g) * DH + d2) * S_LEN + sl;
    vT[vo] = f2bf(v1);
    vT[vo + (size_t)64 * S_LEN] = f2bf(v2);
}

// ---------------- flash attention with sliding window + tanh softcap ----------------
__global__ __launch_bounds__(256, 2) void k_attn(const ushort* __restrict__ q, const ushort* __restrict__ kk,
                                                 const ushort* __restrict__ vT, ushort* __restrict__ O) {
    __shared__ char sK[16384];   // [64 tok][128 d] bf16, swizzled
    __shared__ char sV[16384];   // [128 d][64 tok] bf16, swizzled
    __shared__ char sP[8192];    // per-wave 2KB: [16 q][64 kj] bf16, swizzled
    const int qb = 31 - blockIdx.x;   // heavy blocks first
    const int bh = blockIdx.y;   // 0..31
    const int b = bh >> 4, h = bh & 15, g = h >> 1;
    const int tid = threadIdx.x, l = tid & 63, w = tid >> 6;
    const int qs = qb * 64;
    const int q0 = qs + w * 16;

    const ushort* qbase = q + ((size_t)(b * NH + h) * S_LEN) * DH;
    s16x8 qf[4];
    {
        const char* qrow = (const char*)(qbase + (size_t)(q0 + (l & 15)) * DH);
#pragma unroll
        for (int ds = 0; ds < 4; ++ds)
            qf[ds] = *(const s16x8*)(qrow + ds * 64 + (l >> 4) * 16);
    }
    f32x4 acc[8] = {};
    float lrow[4] = {0.f, 0.f, 0.f, 0.f};

    const size_t kgbase = ((size_t)(b * NKV + g) * S_LEN) * DH * 2;
    const size_t vgbase = ((size_t)(b * NKV + g) * DH) * S_LEN * 2;

    const int jt0 = (qs > 1023) ? ((qs - 1023) >> 6) : 0;
    for (int jt = jt0; jt <= qb; ++jt) {
#pragma unroll
        for (int i = 0; i < 4; ++i) {
            int row = (tid >> 4) + i * 16;
            int colb = (tid & 15) * 16;
            const char* src = (const char*)kk + kgbase + ((size_t)(jt * 64 + row)) * 256 + (colb ^ ((row & 7) << 4));
            g2lds16(src, sK + tid * 16 + i * 4096);
        }
#pragma unroll
        for (int i = 0; i < 4; ++i) {
            int row = (tid >> 3) + i * 32;
            int colb = (tid & 7) * 16;
            const char* src = (const char*)vT + vgbase + (size_t)row * 4096 + (size_t)jt * 128 + (colb ^ ((row & 7) << 4));
            g2lds16(src, sV + tid * 16 + i * 4096);
        }
        __syncthreads();

        f32x4 sc[4];
#pragma unroll
        for (int ct = 0; ct < 4; ++ct) {
            f32x4 z = {};
            int row = ct * 16 + (l & 15);
#pragma unroll
            for (int ds = 0; ds < 4; ++ds) {
                int kb = ds * 64 + (l >> 4) * 16;
                s16x8 kf = *(const s16x8*)(sK + row * 256 + (kb ^ ((row & 7) << 4)));
                z = __builtin_amdgcn_mfma_f32_16x16x32_bf16(qf[ds], kf, z, 0, 0, 0);
            }
            sc[ct] = z;
        }
        // softcap + window mask + fixed-shift exp: p = exp(50*tanh(x/50) - 50) = exp(-100/(exp(2x/50)+1))
        float p[4][4];
#pragma unroll
        for (int ct = 0; ct < 4; ++ct) {
            int j = jt * 64 + ct * 16 + (l & 15);
#pragma unroll
            for (int r = 0; r < 4; ++r) {
                int i_ = qs + w * 16 + (l >> 4) * 4 + r;
                float x = sc[ct][r];
                float e = __expf(x * 0.04f);
                float pe = __expf(-100.f / (e + 1.f));
                bool ok = (j <= i_) && (i_ - j < 1024);
                pe = ok ? pe : 0.f;
                p[ct][r] = pe;
                lrow[r] += pe;
            }
        }
#pragma unroll
        for (int ct = 0; ct < 4; ++ct) {
            int col = ct * 16 + (l & 15);
#pragma unroll
            for (int r = 0; r < 4; ++r) {
                int row = (l >> 4) * 4 + r;
                *(ushort*)(sP + w * 2048 + row * 128 + ((col * 2) ^ ((row & 7) << 4))) = f2bf(p[ct][r]);
            }
        }
#pragma unroll
        for (int s2 = 0; s2 < 2; ++s2) {
            int rowp = l & 15;
            int kb = s2 * 64 + (l >> 4) * 16;
            s16x8 pf = *(const s16x8*)(sP + w * 2048 + rowp * 128 + (kb ^ ((rowp & 7) << 4)));
#pragma unroll
            for (int dt = 0; dt < 8; ++dt) {
                int d = dt * 16 + (l & 15);
                s16x8 vf = *(const s16x8*)(sV + d * 128 + (kb ^ ((d & 7) << 4)));
                acc[dt] = __builtin_amdgcn_mfma_f32_16x16x32_bf16(pf, vf, acc[dt], 0, 0, 0);
            }
        }
        __syncthreads();
    }
#pragma unroll
    for (int r = 0; r < 4; ++r) {
        float rs = lrow[r];
        rs += __shfl_xor(rs, 1); rs += __shfl_xor(rs, 2);
        rs += __shfl_xor(rs, 4); rs += __shfl_xor(rs, 8);
        lrow[r] = rs;
    }
#pragma unroll
    for (int r = 0; r < 4; ++r) {
        int row = qs + w * 16 + (l >> 4) * 4 + r;
        float inv = 1.f / lrow[r];
#pragma unroll
        for (int dt = 0; dt < 8; ++dt)
            O[((size_t)(b * S_LEN + row)) * HID + h * DH + dt * 16 + (l & 15)] = f2bf(acc[dt][r] * inv);
    }
}

extern "C" void kernel_launch(void* const* d_in, const int* in_sizes, int n_in,
                              void* d_out, int out_size, void* d_ws, size_t ws_size,
                              hipStream_t stream) {
    (void)in_sizes; (void)n_in; (void)out_size; (void)ws_size;
    const float* hs  = (const float*)d_in[0];
    const float* WAq = (const float*)d_in[1];
    const float* WBq = (const float*)d_in[2];
    const float* WAk = (const float*)d_in[3];
    const float* WBk = (const float*)d_in[4];
    const float* WAv = (const float*)d_in[5];
    const float* WBv = (const float*)d_in[6];
    const float* Wo  = (const float*)d_in[7];
    const float* fc  = (const float*)d_in[8];
    const float* fs  = (const float*)d_in[9];

    char* ws = (char*)d_ws;
    ushort* Xb    = (ushort*)(ws + 0);            // 4096x2048 bf16       16.78 MB
    ushort* WtS   = (ushort*)(ws + 16777216);     // 640x2048 bf16         2.62 MB
    ushort* WtBq  = (ushort*)(ws + 19398656);     // 12288x2048 bf16      50.33 MB
    ushort* WtWo  = (ushort*)(ws + 69730304);     // 2048x2048 bf16        8.39 MB
    float*  Small = (float*) (ws + 78118912);     // 4096x640 f32         10.49 MB
    ushort* BqC   = (ushort*)(ws + 88604672);     // 4096x3072 bf16       25.17 MB
    ushort* qB    = (ushort*)(ws + 113770496);    // (B,H,S,D) bf16       16.78 MB
    ushort* kB    = (ushort*)(ws + 130547712);    // (B,KV,S,D) bf16       8.39 MB
    ushort* vTB   = (ushort*)(ws + 138936320);    // (B,KV,D,S) bf16       8.39 MB
    ushort* OB    = (ushort*)(ws + 147324928);    // 4096x2048 bf16       16.78 MB

    k_cvt_bf16<<<8192, 256, 0, stream>>>(hs, Xb, 2097152);
    k_transpose_w<<<dim3(32, 2),   256, 0, stream>>>(WAq, WtS, 96, 0);
    k_transpose_w<<<dim3(32, 1),   256, 0, stream>>>(WAk, WtS, 16, 96);
    k_transpose_w<<<dim3(32, 1),   256, 0, stream>>>(WAv, WtS, 16, 112);
    k_transpose_w<<<dim3(32, 4),   256, 0, stream>>>(WBk, WtS, 256, 128);
    k_transpose_w<<<dim3(32, 4),   256, 0, stream>>>(WBv, WtS, 256, 384);
    k_transpose_w<<<dim3(32, 192), 256, 0, stream>>>(WBq, WtBq, 12288, 0);
    k_transpose_w<<<dim3(32, 32),  256, 0, stream>>>(Wo, WtWo, 2048, 0);

    k_gemm<float><<<dim3(32, 5), 256, 0, stream>>>(Xb, WtS, Small, 640);
    k_contract_kv<<<4096, 512, 0, stream>>>(Small, fc, fs, kB, vTB);

    for (int c = 0; c < 4; ++c) {
        k_gemm256<<<192, 512, 0, stream>>>(Xb, WtBq + (size_t)c * 3072 * KG, BqC, 3072);
        k_contract_q<<<4096, 256, 0, stream>>>(BqC, Small, fc, fs, qB, c);
    }

    k_attn<<<dim3(32, 32), 256, 0, stream>>>(qB, kB, vTB, OB);

    k_gemm<float><<<dim3(32, 16), 256, 0, stream>>>(OB, WtWo, (float*)d_out, 2048);
}

// Round 4
// 549.730 us; speedup vs baseline: 1.0095x; 1.0095x over previous
//
#include <hip/hip_runtime.h>
#include <hip/hip_bf16.h>

#define S_LEN 2048
#define HID 2048
#define NB 2
#define NH 16
#define NKV 8
#define DH 128
#define RQ 6
#define KG 2048
#define SCALING 0.08838834764831845f

typedef __attribute__((ext_vector_type(8))) short s16x8;
typedef __attribute__((ext_vector_type(4))) float f32x4;

__device__ __forceinline__ float bf2f(ushort u) {
    union { unsigned int i; float f; } v; v.i = ((unsigned int)u) << 16; return v.f;
}
__device__ __forceinline__ ushort f2bf(float f) {
    __hip_bfloat16 h = __float2bfloat16(f);
    return *reinterpret_cast<ushort*>(&h);
}
__device__ __forceinline__ void g2lds16(const void* g, void* l) {
    __builtin_amdgcn_global_load_lds((const __attribute__((address_space(1))) void*)g,
                                     (__attribute__((address_space(3))) void*)l, 16, 0, 0);
}

// ---------------- fp32 -> bf16 convert (vector) ----------------
__global__ void k_cvt_bf16(const float* __restrict__ in, ushort* __restrict__ out, int n4) {
    int i = blockIdx.x * 256 + threadIdx.x;
    if (i >= n4) return;
    float4 v = ((const float4*)in)[i];
    ushort4 o;
    o.x = f2bf(v.x); o.y = f2bf(v.y); o.z = f2bf(v.z); o.w = f2bf(v.w);
    ((ushort4*)out)[i] = o;
}

// ---------------- weight transpose+convert: in [K=2048][Nin] f32 -> out [(rowOff+n)][2048] bf16 ----------------
__global__ void k_transpose_w(const float* __restrict__ in, ushort* __restrict__ out, int Nin, int rowOff) {
    __shared__ ushort tile[64][66];
    int k0 = blockIdx.x * 64, n0 = blockIdx.y * 64;
    int t = threadIdx.x;
#pragma unroll
    for (int i = 0; i < 16; ++i) {
        int f = t + i * 256; int r = f >> 6, c = f & 63;
        int nn = n0 + c;
        float v = (nn < Nin) ? in[(size_t)(k0 + r) * Nin + nn] : 0.f;
        tile[r][c] = f2bf(v);
    }
    __syncthreads();
#pragma unroll
    for (int i = 0; i < 16; ++i) {
        int f = t + i * 256; int nr = f >> 6, kc = f & 63;
        int nn = n0 + nr;
        if (nn < Nin) out[(size_t)(rowOff + nn) * KG + k0 + kc] = tile[kc][nr];
    }
}

// ---------------- generic bf16 GEMM: A[M][2048] @ Bt[N][2048]^T -> C[M][ldc], 128x128 tile ----------------
__device__ __forceinline__ void stc(float* p, float v) { *p = v; }
__device__ __forceinline__ void stc(ushort* p, float v) { *p = f2bf(v); }

template<typename OutT>
__global__ __launch_bounds__(256, 2) void k_gemm(const ushort* __restrict__ A,
                                                 const ushort* __restrict__ Bt,
                                                 OutT* __restrict__ C, int ldc) {
    __shared__ ushort lA[128 * 64];
    __shared__ ushort lB[128 * 64];
    const int tid = threadIdx.x;
    const int l = tid & 63, w = tid >> 6;
    const int gx = gridDim.x;
    int flat = blockIdx.y * gx + blockIdx.x;
    const int nwg = gx * gridDim.y;
    if ((nwg & 7) == 0) {
        int qq = nwg >> 3;
        flat = (flat & 7) * qq + (flat >> 3);
    }
    const int m0 = (flat % gx) * 128, n0 = (flat / gx) * 128;
    const int wm = w >> 1, wn = w & 1;
    f32x4 acc[4][4] = {};
    const int swz = 16 * ((tid & 7) ^ ((tid >> 3) & 7));
    const int rowbase = tid >> 3;

    for (int k0 = 0; k0 < KG; k0 += 64) {
#pragma unroll
        for (int i = 0; i < 4; ++i) {
            int row = rowbase + i * 32;
            const char* srcA = (const char*)A + (((size_t)(m0 + row) * KG + k0) * 2) + swz;
            g2lds16(srcA, (char*)lA + tid * 16 + i * 4096);
            const char* srcB = (const char*)Bt + (((size_t)(n0 + row) * KG + k0) * 2) + swz;
            g2lds16(srcB, (char*)lB + tid * 16 + i * 4096);
        }
        __syncthreads();
#pragma unroll
        for (int kk = 0; kk < 2; ++kk) {
            s16x8 af[4], bfr[4];
            const int kb = kk * 64 + (l >> 4) * 16;
#pragma unroll
            for (int mf = 0; mf < 4; ++mf) {
                int row = wm * 64 + mf * 16 + (l & 15);
                af[mf] = *(const s16x8*)((const char*)lA + row * 128 + (kb ^ ((row & 7) << 4)));
            }
#pragma unroll
            for (int nf = 0; nf < 4; ++nf) {
                int row = wn * 64 + nf * 16 + (l & 15);
                bfr[nf] = *(const s16x8*)((const char*)lB + row * 128 + (kb ^ ((row & 7) << 4)));
            }
#pragma unroll
            for (int mf = 0; mf < 4; ++mf)
#pragma unroll
                for (int nf = 0; nf < 4; ++nf)
                    acc[mf][nf] = __builtin_amdgcn_mfma_f32_16x16x32_bf16(af[mf], bfr[nf], acc[mf][nf], 0, 0, 0);
        }
        __syncthreads();
    }
#pragma unroll
    for (int mf = 0; mf < 4; ++mf)
#pragma unroll
        for (int r = 0; r < 4; ++r) {
            int row = m0 + wm * 64 + mf * 16 + (l >> 4) * 4 + r;
#pragma unroll
            for (int nf = 0; nf < 4; ++nf) {
                int col = n0 + wn * 64 + nf * 16 + (l & 15);
                stc(C + (size_t)row * ldc + col, acc[mf][nf][r]);
            }
        }
}

// ---------------- contract ranks + rope + scale for q (one Bq chunk of 4 heads) ----------------
__global__ void k_contract_q(const ushort* __restrict__ bq, const float* __restrict__ small,
                             const float* __restrict__ cosT, const float* __restrict__ sinT,
                             ushort* __restrict__ q, int chunk) {
    int srow = blockIdx.x;               // 0..4095 == b*2048 + s
    int b = srow >> 11, sl = srow & 2047;
    int t = threadIdx.x;
    int d2 = t & 63, hp = t >> 6;        // hp 0..3
    int h = chunk * 4 + hp;
    const ushort* bqr = bq + (size_t)srow * 3072 + hp * 768;
    const float* af = small + (size_t)srow * 640 + h * RQ;
    float x1 = 0.f, x2 = 0.f;
#pragma unroll
    for (int r = 0; r < RQ; ++r) {
        float a = af[r];
        x1 += a * bf2f(bqr[r * 128 + d2]);
        x2 += a * bf2f(bqr[r * 128 + 64 + d2]);
    }
    float c = cosT[sl * 64 + d2], s = sinT[sl * 64 + d2];
    float q1 = (x1 * c - x2 * s) * SCALING;
    float q2 = (x1 * s + x2 * c) * SCALING;
    size_t o = ((size_t)(b * NH + h) * S_LEN + sl) * DH + d2;
    q[o] = f2bf(q1);
    q[o + 64] = f2bf(q2);
}

// ---------------- contract ranks for k (rope) and v (write v^T) ----------------
__global__ void k_contract_kv(const float* __restrict__ small, const float* __restrict__ cosT,
                              const float* __restrict__ sinT, ushort* __restrict__ kk,
                              ushort* __restrict__ vT) {
    int srow = blockIdx.x;
    int b = srow >> 11, sl = srow & 2047;
    int t = threadIdx.x;                 // 512 threads
    int d2 = t & 63, g = t >> 6;         // g 0..7
    const float* row = small + (size_t)srow * 640;
    float k1 = 0.f, k2 = 0.f, v1 = 0.f, v2 = 0.f;
#pragma unroll
    for (int r = 0; r < 2; ++r) {
        float ak = row[96 + g * 2 + r];
        k1 += ak * row[128 + r * 128 + d2];
        k2 += ak * row[128 + r * 128 + 64 + d2];
        float av = row[112 + g * 2 + r];
        v1 += av * row[384 + r * 128 + d2];
        v2 += av * row[384 + r * 128 + 64 + d2];
    }
    float c = cosT[sl * 64 + d2], s = sinT[sl * 64 + d2];
    float kr1 = k1 * c - k2 * s, kr2 = k1 * s + k2 * c;
    size_t ko = ((size_t)(b * NKV + g) * S_LEN + sl) * DH + d2;
    kk[ko] = f2bf(kr1);
    kk[ko + 64] = f2bf(kr2);
    size_t vo = ((size_t)(b * NKV + g) * DH + d2) * S_LEN + sl;
    vT[vo] = f2bf(v1);
    vT[vo + (size_t)64 * S_LEN] = f2bf(v2);
}

// ---------------- flash attention: sliding window + tanh softcap, double-buffered K/V ----------------
// Fixed-shift softmax (scores capped at 50). 2-slot LDS ring: stage(jt+1) issued BEFORE
// compute(jt); vmcnt(0)+s_barrier only AFTER compute, so staging latency hides under
// QK/softcap/PV. Slot written at jt+1 was last read before jt's end barrier.
__global__ __launch_bounds__(256, 2) void k_attn(const ushort* __restrict__ q, const ushort* __restrict__ kk,
                                                 const ushort* __restrict__ vT, ushort* __restrict__ O) {
    __shared__ char sK[2][16384];   // [64 tok][128 d] bf16, swizzled
    __shared__ char sV[2][16384];   // [128 d][64 tok] bf16, swizzled
    __shared__ char sP[8192];       // per-wave 2KB: [16 q][64 kj] bf16, swizzled
    const int qb = 31 - blockIdx.x; // heavy blocks first
    const int bh = blockIdx.y;      // 0..31
    const int b = bh >> 4, h = bh & 15, g = h >> 1;
    const int tid = threadIdx.x, l = tid & 63, w = tid >> 6;
    const int qs = qb * 64;
    const int q0 = qs + w * 16;

    const ushort* qbase = q + ((size_t)(b * NH + h) * S_LEN) * DH;
    s16x8 qf[4];
    {
        const char* qrow = (const char*)(qbase + (size_t)(q0 + (l & 15)) * DH);
#pragma unroll
        for (int ds = 0; ds < 4; ++ds)
            qf[ds] = *(const s16x8*)(qrow + ds * 64 + (l >> 4) * 16);
    }
    f32x4 acc[8] = {};
    float lrow[4] = {0.f, 0.f, 0.f, 0.f};

    const size_t kgbase = ((size_t)(b * NKV + g) * S_LEN) * DH * 2;
    const size_t vgbase = ((size_t)(b * NKV + g) * DH) * S_LEN * 2;

    // jt-invariant staging offsets
    const int krow = tid >> 4, kcolb = (tid & 15) * 16;
    const int vrow = tid >> 3, vcolb = (tid & 7) * 16;

#define STAGE_KV(JT, SLOT)                                                                  \
    do {                                                                                     \
        _Pragma("unroll")                                                                    \
        for (int i = 0; i < 4; ++i) {                                                        \
            int row = krow + i * 16;                                                         \
            const char* src = (const char*)kk + kgbase + ((size_t)((JT) * 64 + row)) * 256   \
                              + (kcolb ^ ((row & 7) << 4));                                  \
            g2lds16(src, &sK[SLOT][tid * 16 + i * 4096]);                                    \
        }                                                                                    \
        _Pragma("unroll")                                                                    \
        for (int i = 0; i < 4; ++i) {                                                        \
            int row = vrow + i * 32;                                                         \
            const char* src = (const char*)vT + vgbase + (size_t)row * 4096                  \
                              + (size_t)(JT) * 128 + (vcolb ^ ((row & 7) << 4));             \
            g2lds16(src, &sV[SLOT][tid * 16 + i * 4096]);                                    \
        }                                                                                    \
    } while (0)

    const int jt0 = (qs > 1023) ? ((qs - 1023) >> 6) : 0;
    STAGE_KV(jt0, 0);
    asm volatile("s_waitcnt vmcnt(0)" ::: "memory");
    __builtin_amdgcn_s_barrier();
    asm volatile("" ::: "memory");

    for (int jt = jt0; jt <= qb; ++jt) {
        const int cur = (jt - jt0) & 1;
        if (jt < qb) STAGE_KV(jt + 1, cur ^ 1);

        // QK^T: 16 q-rows x 64 keys per wave
        f32x4 sc[4];
#pragma unroll
        for (int ct = 0; ct < 4; ++ct) {
            f32x4 z = {};
            int row = ct * 16 + (l & 15);
#pragma unroll
            for (int ds = 0; ds < 4; ++ds) {
                int kb = ds * 64 + (l >> 4) * 16;
                s16x8 kf = *(const s16x8*)(&sK[cur][row * 256 + (kb ^ ((row & 7) << 4))]);
                z = __builtin_amdgcn_mfma_f32_16x16x32_bf16(qf[ds], kf, z, 0, 0, 0);
            }
            sc[ct] = z;
        }
        // softcap + window mask + fixed-shift exp: p = exp(50*tanh(x/50)-50) = exp(-100/(exp(2x/50)+1))
        float p[4][4];
#pragma unroll
        for (int ct = 0; ct < 4; ++ct) {
            int j = jt * 64 + ct * 16 + (l & 15);
#pragma unroll
            for (int r = 0; r < 4; ++r) {
                int i_ = qs + w * 16 + (l >> 4) * 4 + r;
                float x = sc[ct][r];
                float e = __expf(x * 0.04f);
                float pe = __expf(-100.f / (e + 1.f));
                bool ok = (j <= i_) && (i_ - j < 1024);
                pe = ok ? pe : 0.f;
                p[ct][r] = pe;
                lrow[r] += pe;
            }
        }
        // P -> per-wave LDS (bf16, swizzled)
#pragma unroll
        for (int ct = 0; ct < 4; ++ct) {
            int col = ct * 16 + (l & 15);
#pragma unroll
            for (int r = 0; r < 4; ++r) {
                int row = (l >> 4) * 4 + r;
                *(ushort*)(sP + w * 2048 + row * 128 + ((col * 2) ^ ((row & 7) << 4))) = f2bf(p[ct][r]);
            }
        }
        // PV
#pragma unroll
        for (int s2 = 0; s2 < 2; ++s2) {
            int rowp = l & 15;
            int kb = s2 * 64 + (l >> 4) * 16;
            s16x8 pf = *(const s16x8*)(sP + w * 2048 + rowp * 128 + (kb ^ ((rowp & 7) << 4)));
#pragma unroll
            for (int dt = 0; dt < 8; ++dt) {
                int d = dt * 16 + (l & 15);
                s16x8 vf = *(const s16x8*)(&sV[cur][d * 128 + (kb ^ ((d & 7) << 4))]);
                acc[dt] = __builtin_amdgcn_mfma_f32_16x16x32_bf16(pf, vf, acc[dt], 0, 0, 0);
            }
        }

        asm volatile("s_waitcnt vmcnt(0)" ::: "memory");
        __builtin_amdgcn_s_barrier();
        asm volatile("" ::: "memory");
    }
#undef STAGE_KV

#pragma unroll
    for (int r = 0; r < 4; ++r) {
        float rs = lrow[r];
        rs += __shfl_xor(rs, 1); rs += __shfl_xor(rs, 2);
        rs += __shfl_xor(rs, 4); rs += __shfl_xor(rs, 8);
        lrow[r] = rs;
    }
#pragma unroll
    for (int r = 0; r < 4; ++r) {
        int row = qs + w * 16 + (l >> 4) * 4 + r;
        float inv = 1.f / lrow[r];
#pragma unroll
        for (int dt = 0; dt < 8; ++dt)
            O[((size_t)(b * S_LEN + row)) * HID + h * DH + dt * 16 + (l & 15)] = f2bf(acc[dt][r] * inv);
    }
}

extern "C" void kernel_launch(void* const* d_in, const int* in_sizes, int n_in,
                              void* d_out, int out_size, void* d_ws, size_t ws_size,
                              hipStream_t stream) {
    (void)in_sizes; (void)n_in; (void)out_size; (void)ws_size;
    const float* hs  = (const float*)d_in[0];
    const float* WAq = (const float*)d_in[1];
    const float* WBq = (const float*)d_in[2];
    const float* WAk = (const float*)d_in[3];
    const float* WBk = (const float*)d_in[4];
    const float* WAv = (const float*)d_in[5];
    const float* WBv = (const float*)d_in[6];
    const float* Wo  = (const float*)d_in[7];
    const float* fc  = (const float*)d_in[8];
    const float* fs  = (const float*)d_in[9];

    char* ws = (char*)d_ws;
    ushort* Xb    = (ushort*)(ws + 0);            // 4096x2048 bf16       16.78 MB
    ushort* WtS   = (ushort*)(ws + 16777216);     // 640x2048 bf16         2.62 MB
    ushort* WtBq  = (ushort*)(ws + 19398656);     // 12288x2048 bf16      50.33 MB
    ushort* WtWo  = (ushort*)(ws + 69730304);     // 2048x2048 bf16        8.39 MB
    float*  Small = (float*) (ws + 78118912);     // 4096x640 f32         10.49 MB
    ushort* BqC   = (ushort*)(ws + 88604672);     // 4096x3072 bf16       25.17 MB
    ushort* qB    = (ushort*)(ws + 113770496);    // (B,H,S,D) bf16       16.78 MB
    ushort* kB    = (ushort*)(ws + 130547712);    // (B,KV,S,D) bf16       8.39 MB
    ushort* vTB   = (ushort*)(ws + 138936320);    // (B,KV,D,S) bf16       8.39 MB
    ushort* OB    = (ushort*)(ws + 147324928);    // 4096x2048 bf16       16.78 MB

    k_cvt_bf16<<<8192, 256, 0, stream>>>(hs, Xb, 2097152);
    k_transpose_w<<<dim3(32, 2),   256, 0, stream>>>(WAq, WtS, 96, 0);
    k_transpose_w<<<dim3(32, 1),   256, 0, stream>>>(WAk, WtS, 16, 96);
    k_transpose_w<<<dim3(32, 1),   256, 0, stream>>>(WAv, WtS, 16, 112);
    k_transpose_w<<<dim3(32, 4),   256, 0, stream>>>(WBk, WtS, 256, 128);
    k_transpose_w<<<dim3(32, 4),   256, 0, stream>>>(WBv, WtS, 256, 384);
    k_transpose_w<<<dim3(32, 192), 256, 0, stream>>>(WBq, WtBq, 12288, 0);
    k_transpose_w<<<dim3(32, 32),  256, 0, stream>>>(Wo, WtWo, 2048, 0);

    k_gemm<float><<<dim3(32, 5), 256, 0, stream>>>(Xb, WtS, Small, 640);
    k_contract_kv<<<4096, 512, 0, stream>>>(Small, fc, fs, kB, vTB);

    for (int c = 0; c < 4; ++c) {
        k_gemm<ushort><<<dim3(32, 24), 256, 0, stream>>>(Xb, WtBq + (size_t)c * 3072 * KG, BqC, 3072);
        k_contract_q<<<4096, 256, 0, stream>>>(BqC, Small, fc, fs, qB, c);
    }

    k_attn<<<dim3(32, 32), 256, 0, stream>>>(qB, kB, vTB, OB);

    k_gemm<float><<<dim3(32, 16), 256, 0, stream>>>(OB, WtWo, (float*)d_out, 2048);
}

// Round 5
// 537.401 us; speedup vs baseline: 1.0326x; 1.0229x over previous
//
#include <hip/hip_runtime.h>
#include <hip/hip_bf16.h>

#define S_LEN 2048
#define HID 2048
#define NB 2
#define NH 16
#define NKV 8
#define DH 128
#define RQ 6
#define KG 2048
#define SCALING 0.08838834764831845f

typedef __attribute__((ext_vector_type(8))) short s16x8;
typedef __attribute__((ext_vector_type(4))) float f32x4;

__device__ __forceinline__ float bf2f(ushort u) {
    union { unsigned int i; float f; } v; v.i = ((unsigned int)u) << 16; return v.f;
}
__device__ __forceinline__ ushort f2bf(float f) {
    __hip_bfloat16 h = __float2bfloat16(f);
    return *reinterpret_cast<ushort*>(&h);
}
__device__ __forceinline__ void g2lds16(const void* g, void* l) {
    __builtin_amdgcn_global_load_lds((const __attribute__((address_space(1))) void*)g,
                                     (__attribute__((address_space(3))) void*)l, 16, 0, 0);
}

// ---------------- fp32 -> bf16 convert (vector) ----------------
__global__ void k_cvt_bf16(const float* __restrict__ in, ushort* __restrict__ out, int n4) {
    int i = blockIdx.x * 256 + threadIdx.x;
    if (i >= n4) return;
    float4 v = ((const float4*)in)[i];
    ushort4 o;
    o.x = f2bf(v.x); o.y = f2bf(v.y); o.z = f2bf(v.z); o.w = f2bf(v.w);
    ((ushort4*)out)[i] = o;
}

// ---------------- weight transpose+convert: in [K=2048][Nin] f32 -> out [(rowOff+n)][2048] bf16 ----------------
__global__ void k_transpose_w(const float* __restrict__ in, ushort* __restrict__ out, int Nin, int rowOff) {
    __shared__ ushort tile[64][66];
    int k0 = blockIdx.x * 64, n0 = blockIdx.y * 64;
    int t = threadIdx.x;
#pragma unroll
    for (int i = 0; i < 16; ++i) {
        int f = t + i * 256; int r = f >> 6, c = f & 63;
        int nn = n0 + c;
        float v = (nn < Nin) ? in[(size_t)(k0 + r) * Nin + nn] : 0.f;
        tile[r][c] = f2bf(v);
    }
    __syncthreads();
#pragma unroll
    for (int i = 0; i < 16; ++i) {
        int f = t + i * 256; int nr = f >> 6, kc = f & 63;
        int nn = n0 + nr;
        if (nn < Nin) out[(size_t)(rowOff + nn) * KG + k0 + kc] = tile[kc][nr];
    }
}

// ---------------- generic bf16 GEMM: A[M][2048] @ Bt[N][2048]^T -> C[M][ldc], 128x128 tile ----------------
__device__ __forceinline__ void stc(float* p, float v) { *p = v; }
__device__ __forceinline__ void stc(ushort* p, float v) { *p = f2bf(v); }

template<typename OutT>
__global__ __launch_bounds__(256, 2) void k_gemm(const ushort* __restrict__ A,
                                                 const ushort* __restrict__ Bt,
                                                 OutT* __restrict__ C, int ldc) {
    __shared__ ushort lA[128 * 64];
    __shared__ ushort lB[128 * 64];
    const int tid = threadIdx.x;
    const int l = tid & 63, w = tid >> 6;
    const int gx = gridDim.x;
    int flat = blockIdx.y * gx + blockIdx.x;
    const int nwg = gx * gridDim.y;
    if ((nwg & 7) == 0) {
        int qq = nwg >> 3;
        flat = (flat & 7) * qq + (flat >> 3);
    }
    const int m0 = (flat % gx) * 128, n0 = (flat / gx) * 128;
    const int wm = w >> 1, wn = w & 1;
    f32x4 acc[4][4] = {};
    const int swz = 16 * ((tid & 7) ^ ((tid >> 3) & 7));
    const int rowbase = tid >> 3;

    for (int k0 = 0; k0 < KG; k0 += 64) {
#pragma unroll
        for (int i = 0; i < 4; ++i) {
            int row = rowbase + i * 32;
            const char* srcA = (const char*)A + (((size_t)(m0 + row) * KG + k0) * 2) + swz;
            g2lds16(srcA, (char*)lA + tid * 16 + i * 4096);
            const char* srcB = (const char*)Bt + (((size_t)(n0 + row) * KG + k0) * 2) + swz;
            g2lds16(srcB, (char*)lB + tid * 16 + i * 4096);
        }
        __syncthreads();
#pragma unroll
        for (int kk = 0; kk < 2; ++kk) {
            s16x8 af[4], bfr[4];
            const int kb = kk * 64 + (l >> 4) * 16;
#pragma unroll
            for (int mf = 0; mf < 4; ++mf) {
                int row = wm * 64 + mf * 16 + (l & 15);
                af[mf] = *(const s16x8*)((const char*)lA + row * 128 + (kb ^ ((row & 7) << 4)));
            }
#pragma unroll
            for (int nf = 0; nf < 4; ++nf) {
                int row = wn * 64 + nf * 16 + (l & 15);
                bfr[nf] = *(const s16x8*)((const char*)lB + row * 128 + (kb ^ ((row & 7) << 4)));
            }
#pragma unroll
            for (int mf = 0; mf < 4; ++mf)
#pragma unroll
                for (int nf = 0; nf < 4; ++nf)
                    acc[mf][nf] = __builtin_amdgcn_mfma_f32_16x16x32_bf16(af[mf], bfr[nf], acc[mf][nf], 0, 0, 0);
        }
        __syncthreads();
    }
#pragma unroll
    for (int mf = 0; mf < 4; ++mf)
#pragma unroll
        for (int r = 0; r < 4; ++r) {
            int row = m0 + wm * 64 + mf * 16 + (l >> 4) * 4 + r;
#pragma unroll
            for (int nf = 0; nf < 4; ++nf) {
                int col = n0 + wn * 64 + nf * 16 + (l & 15);
                stc(C + (size_t)row * ldc + col, acc[mf][nf][r]);
            }
        }
}

// ---------------- 256x256 8-phase counted-vmcnt GEMM (BK=64, dbuf, T2+T3+T4+T5) ----------------
// M=4096 fixed (16 m-tiles). A[M][2048] @ Bt[N][2048]^T -> C[M][ldc] bf16. 512 thr, 8 waves 2Mx4N.
// LDS 128KB: dbuf d at d*65536; A region 32KB as halves h (=quadrant mq rows {h*64..+64} u {128+h*64..}),
// B at +32768 as halves h (=quadrant nq rows, 32-row interleave). One half-tile staged per phase
// (2 g2lds/thread); vmcnt(6) at ph4/ph8 (FIFO: 14 outstanding, oldest 8 = next K-tile done).
__global__ __launch_bounds__(512, 2) void k_gemm8(const ushort* __restrict__ A,
                                                  const ushort* __restrict__ Bt,
                                                  ushort* __restrict__ C, int ldc) {
    __shared__ char sB[131072];
    const int tid = threadIdx.x;
    const int l = tid & 63, wid = tid >> 6;
    const int wr = wid >> 2, wc = wid & 3;

    int flat = blockIdx.x;
    const int nwg = gridDim.x;
    if ((nwg & 7) == 0) {
        int qq = nwg >> 3;
        flat = (flat & 7) * qq + (flat >> 3);
    }
    const int m0 = (flat & 15) * 256;
    const int n0 = (flat >> 4) * 256;

    const int rb = tid >> 3;
    const int swz = 16 * ((tid & 7) ^ (rb & 7));
    // stage source pointers: A-half h load j -> row j*128 + h*64 + rb
    const char* pAh[2][2];
    const char* pBh[2][2];
#pragma unroll
    for (int h = 0; h < 2; ++h)
#pragma unroll
        for (int j = 0; j < 2; ++j) {
            pAh[h][j] = (const char*)A + (size_t)(m0 + j * 128 + h * 64 + rb) * (KG * 2) + swz;
            pBh[h][j] = (const char*)Bt + (size_t)(n0 + (j * 2 + (tid >> 8)) * 64 + h * 32 + (rb & 31)) * (KG * 2) + swz;
        }

    f32x4 acc[8][4] = {};
    s16x8 af[4][2], bf[4][2];

    // read-side lane constants
    const int arow = (l & 15) * 128;
    const int kxor0 = (0 * 64 + (l >> 4) * 16) ^ ((l & 7) << 4);
    const int kxor1 = (1 * 64 + (l >> 4) * 16) ^ ((l & 7) << 4);

#define STG_A(T, D, H)                                                                     \
    do {                                                                                   \
        g2lds16(pAh[H][0] + (size_t)(T) * 128, sB + (D) * 65536 + (H) * 16384 + tid * 16); \
        g2lds16(pAh[H][1] + (size_t)(T) * 128, sB + (D) * 65536 + (H) * 16384 + 8192 + tid * 16); \
    } while (0)
#define STG_B(T, D, H)                                                                     \
    do {                                                                                   \
        g2lds16(pBh[H][0] + (size_t)(T) * 128, sB + (D) * 65536 + 32768 + (H) * 16384 + tid * 16); \
        g2lds16(pBh[H][1] + (size_t)(T) * 128, sB + (D) * 65536 + 32768 + (H) * 16384 + 8192 + tid * 16); \
    } while (0)
#define RD_A(D, MH)                                                                        \
    do {                                                                                   \
        const char* ab = sB + (D) * 65536 + (MH) * 16384 + wr * 8192;                      \
        _Pragma("unroll") for (int mi = 0; mi < 4; ++mi) {                                 \
            af[mi][0] = *(const s16x8*)(ab + mi * 2048 + arow + kxor0);                    \
            af[mi][1] = *(const s16x8*)(ab + mi * 2048 + arow + kxor1);                    \
        }                                                                                  \
    } while (0)
#define RD_B(D, BH)                                                                        \
    do {                                                                                   \
        const char* bb = sB + (D) * 65536 + 32768 + (BH) * 16384 + wc * 4096;              \
        _Pragma("unroll") for (int ni = 0; ni < 2; ++ni) {                                 \
            bf[(BH) * 2 + ni][0] = *(const s16x8*)(bb + ni * 2048 + arow + kxor0);         \
            bf[(BH) * 2 + ni][1] = *(const s16x8*)(bb + ni * 2048 + arow + kxor1);         \
        }                                                                                  \
    } while (0)
#define QMFMA(MQ, NQ)                                                                      \
    do {                                                                                   \
        __builtin_amdgcn_s_setprio(1);                                                     \
        _Pragma("unroll") for (int mi = 0; mi < 4; ++mi)                                   \
        _Pragma("unroll") for (int ni = 0; ni < 2; ++ni)                                   \
        _Pragma("unroll") for (int k2 = 0; k2 < 2; ++k2)                                   \
            acc[(MQ) * 4 + mi][(NQ) * 2 + ni] = __builtin_amdgcn_mfma_f32_16x16x32_bf16(   \
                af[mi][k2], bf[(NQ) * 2 + ni][k2], acc[(MQ) * 4 + mi][(NQ) * 2 + ni], 0, 0, 0); \
        __builtin_amdgcn_s_setprio(0);                                                     \
    } while (0)
#define BAR()                                   \
    do {                                        \
        asm volatile("" ::: "memory");          \
        __builtin_amdgcn_s_barrier();           \
        asm volatile("" ::: "memory");          \
    } while (0)
#define VM6() asm volatile("s_waitcnt vmcnt(6)" ::: "memory")
#define VM0() asm volatile("s_waitcnt vmcnt(0)" ::: "memory")

    // prologue: T0 full -> d0; T1 {B0,B1,A0} -> d1  (T1.A1 staged at iter0 ph1)
    STG_A(0, 0, 0); STG_A(0, 0, 1); STG_B(0, 0, 0); STG_B(0, 0, 1);
    STG_B(1, 1, 0); STG_B(1, 1, 1); STG_A(1, 1, 0);
    VM6();
    BAR();

    for (int i = 0; i < 16; ++i) {
        const bool last = (i == 15);
        const int t1 = 2 * i + 1, t2 = 2 * i + 2, t3 = 2 * i + 3;
        // ph1: Q(0,0) of tile 2i (d0)
        RD_A(0, 0); RD_B(0, 0);
        STG_A(t1, 1, 1);
        BAR(); QMFMA(0, 0); BAR();
        // ph2: Q(0,1)
        RD_B(0, 1);
        if (!last) STG_A(t2, 0, 0);
        BAR(); QMFMA(0, 1); BAR();
        // ph3: Q(1,1)
        RD_A(0, 1);
        if (!last) STG_B(t2, 0, 0);
        BAR(); QMFMA(1, 1); BAR();
        // ph4: Q(1,0); tile 2i+1 must be landed for ph5
        if (!last) { STG_B(t2, 0, 1); VM6(); } else { VM0(); }
        BAR(); QMFMA(1, 0); BAR();
        // ph5: Q(0,0) of tile 2i+1 (d1)
        RD_A(1, 0); RD_B(1, 0);
        if (!last) STG_A(t2, 0, 1);
        BAR(); QMFMA(0, 0); BAR();
        // ph6: Q(0,1)
        RD_B(1, 1);
        if (!last) STG_B(t3, 1, 0);
        BAR(); QMFMA(0, 1); BAR();
        // ph7: Q(1,1)
        RD_A(1, 1);
        if (!last) STG_B(t3, 1, 1);
        BAR(); QMFMA(1, 1); BAR();
        // ph8: Q(1,0); tile 2i+2 must be landed for next ph1
        if (!last) { STG_A(t3, 1, 0); VM6(); }
        BAR(); QMFMA(1, 0); BAR();
    }

#undef STG_A
#undef STG_B
#undef RD_A
#undef RD_B
#undef QMFMA
#undef BAR
#undef VM6
#undef VM0

    // epilogue
#pragma unroll
    for (int mf = 0; mf < 8; ++mf)
#pragma unroll
        for (int r = 0; r < 4; ++r) {
            int row = m0 + wr * 128 + mf * 16 + (l >> 4) * 4 + r;
#pragma unroll
            for (int nf = 0; nf < 4; ++nf) {
                int col = n0 + wc * 64 + nf * 16 + (l & 15);
                C[(size_t)row * ldc + col] = f2bf(acc[mf][nf][r]);
            }
        }
}

// ---------------- contract ranks + rope + scale for q (one Bq chunk of 4 heads) ----------------
__global__ void k_contract_q(const ushort* __restrict__ bq, const float* __restrict__ small,
                             const float* __restrict__ cosT, const float* __restrict__ sinT,
                             ushort* __restrict__ q, int chunk) {
    int srow = blockIdx.x;               // 0..4095 == b*2048 + s
    int b = srow >> 11, sl = srow & 2047;
    int t = threadIdx.x;
    int d2 = t & 63, hp = t >> 6;        // hp 0..3
    int h = chunk * 4 + hp;
    const ushort* bqr = bq + (size_t)srow * 3072 + hp * 768;
    const float* af = small + (size_t)srow * 640 + h * RQ;
    float x1 = 0.f, x2 = 0.f;
#pragma unroll
    for (int r = 0; r < RQ; ++r) {
        float a = af[r];
        x1 += a * bf2f(bqr[r * 128 + d2]);
        x2 += a * bf2f(bqr[r * 128 + 64 + d2]);
    }
    float c = cosT[sl * 64 + d2], s = sinT[sl * 64 + d2];
    float q1 = (x1 * c - x2 * s) * SCALING;
    float q2 = (x1 * s + x2 * c) * SCALING;
    size_t o = ((size_t)(b * NH + h) * S_LEN + sl) * DH + d2;
    q[o] = f2bf(q1);
    q[o + 64] = f2bf(q2);
}

// ---------------- contract ranks for k (rope) and v (write v^T) ----------------
__global__ void k_contract_kv(const float* __restrict__ small, const float* __restrict__ cosT,
                              const float* __restrict__ sinT, ushort* __restrict__ kk,
                              ushort* __restrict__ vT) {
    int srow = blockIdx.x;
    int b = srow >> 11, sl = srow & 2047;
    int t = threadIdx.x;                 // 512 threads
    int d2 = t & 63, g = t >> 6;         // g 0..7
    const float* row = small + (size_t)srow * 640;
    float k1 = 0.f, k2 = 0.f, v1 = 0.f, v2 = 0.f;
#pragma unroll
    for (int r = 0; r < 2; ++r) {
        float ak = row[96 + g * 2 + r];
        k1 += ak * row[128 + r * 128 + d2];
        k2 += ak * row[128 + r * 128 + 64 + d2];
        float av = row[112 + g * 2 + r];
        v1 += av * row[384 + r * 128 + d2];
        v2 += av * row[384 + r * 128 + 64 + d2];
    }
    float c = cosT[sl * 64 + d2], s = sinT[sl * 64 + d2];
    float kr1 = k1 * c - k2 * s, kr2 = k1 * s + k2 * c;
    size_t ko = ((size_t)(b * NKV + g) * S_LEN + sl) * DH + d2;
    kk[ko] = f2bf(kr1);
    kk[ko + 64] = f2bf(kr2);
    size_t vo = ((size_t)(b * NKV + g) * DH + d2) * S_LEN + sl;
    vT[vo] = f2bf(v1);
    vT[vo + (size_t)64 * S_LEN] = f2bf(v2);
}

// ---------------- flash attention with sliding window + tanh softcap (R2 version) ----------------
// Fixed-shift softmax: scores capped at <=50, shift m=50. 40KB LDS -> 4 blocks/CU (TLP hides staging).
__global__ __launch_bounds__(256, 2) void k_attn(const ushort* __restrict__ q, const ushort* __restrict__ kk,
                                                 const ushort* __restrict__ vT, ushort* __restrict__ O) {
    __shared__ char sK[16384];   // [64 tok][128 d] bf16, swizzled
    __shared__ char sV[16384];   // [128 d][64 tok] bf16, swizzled
    __shared__ char sP[8192];    // per-wave 2KB: [16 q][64 kj] bf16, swizzled
    const int qb = 31 - blockIdx.x;   // heavy blocks first
    const int bh = blockIdx.y;   // 0..31
    const int b = bh >> 4, h = bh & 15, g = h >> 1;
    const int tid = threadIdx.x, l = tid & 63, w = tid >> 6;
    const int qs = qb * 64;
    const int q0 = qs + w * 16;

    const ushort* qbase = q + ((size_t)(b * NH + h) * S_LEN) * DH;
    s16x8 qf[4];
    {
        const char* qrow = (const char*)(qbase + (size_t)(q0 + (l & 15)) * DH);
#pragma unroll
        for (int ds = 0; ds < 4; ++ds)
            qf[ds] = *(const s16x8*)(qrow + ds * 64 + (l >> 4) * 16);
    }
    f32x4 acc[8] = {};
    float lrow[4] = {0.f, 0.f, 0.f, 0.f};

    const size_t kgbase = ((size_t)(b * NKV + g) * S_LEN) * DH * 2;
    const size_t vgbase = ((size_t)(b * NKV + g) * DH) * S_LEN * 2;

    const int jt0 = (qs > 1023) ? ((qs - 1023) >> 6) : 0;
    for (int jt = jt0; jt <= qb; ++jt) {
#pragma unroll
        for (int i = 0; i < 4; ++i) {
            int row = (tid >> 4) + i * 16;
            int colb = (tid & 15) * 16;
            const char* src = (const char*)kk + kgbase + ((size_t)(jt * 64 + row)) * 256 + (colb ^ ((row & 7) << 4));
            g2lds16(src, sK + tid * 16 + i * 4096);
        }
#pragma unroll
        for (int i = 0; i < 4; ++i) {
            int row = (tid >> 3) + i * 32;
            int colb = (tid & 7) * 16;
            const char* src = (const char*)vT + vgbase + (size_t)row * 4096 + (size_t)jt * 128 + (colb ^ ((row & 7) << 4));
            g2lds16(src, sV + tid * 16 + i * 4096);
        }
        __syncthreads();

        f32x4 sc[4];
#pragma unroll
        for (int ct = 0; ct < 4; ++ct) {
            f32x4 z = {};
            int row = ct * 16 + (l & 15);
#pragma unroll
            for (int ds = 0; ds < 4; ++ds) {
                int kb = ds * 64 + (l >> 4) * 16;
                s16x8 kf = *(const s16x8*)(sK + row * 256 + (kb ^ ((row & 7) << 4)));
                z = __builtin_amdgcn_mfma_f32_16x16x32_bf16(qf[ds], kf, z, 0, 0, 0);
            }
            sc[ct] = z;
        }
        // softcap + window mask + fixed-shift exp: p = exp(50*tanh(x/50)-50) = exp(-100/(exp(2x/50)+1))
        float p[4][4];
#pragma unroll
        for (int ct = 0; ct < 4; ++ct) {
            int j = jt * 64 + ct * 16 + (l & 15);
#pragma unroll
            for (int r = 0; r < 4; ++r) {
                int i_ = qs + w * 16 + (l >> 4) * 4 + r;
                float x = sc[ct][r];
                float e = __expf(x * 0.04f);
                float pe = __expf(-100.f / (e + 1.f));
                bool ok = (j <= i_) && (i_ - j < 1024);
                pe = ok ? pe : 0.f;
                p[ct][r] = pe;
                lrow[r] += pe;
            }
        }
#pragma unroll
        for (int ct = 0; ct < 4; ++ct) {
            int col = ct * 16 + (l & 15);
#pragma unroll
            for (int r = 0; r < 4; ++r) {
                int row = (l >> 4) * 4 + r;
                *(ushort*)(sP + w * 2048 + row * 128 + ((col * 2) ^ ((row & 7) << 4))) = f2bf(p[ct][r]);
            }
        }
#pragma unroll
        for (int s2 = 0; s2 < 2; ++s2) {
            int rowp = l & 15;
            int kb = s2 * 64 + (l >> 4) * 16;
            s16x8 pf = *(const s16x8*)(sP + w * 2048 + rowp * 128 + (kb ^ ((rowp & 7) << 4)));
#pragma unroll
            for (int dt = 0; dt < 8; ++dt) {
                int d = dt * 16 + (l & 15);
                s16x8 vf = *(const s16x8*)(sV + d * 128 + (kb ^ ((d & 7) << 4)));
                acc[dt] = __builtin_amdgcn_mfma_f32_16x16x32_bf16(pf, vf, acc[dt], 0, 0, 0);
            }
        }
        __syncthreads();
    }
#pragma unroll
    for (int r = 0; r < 4; ++r) {
        float rs = lrow[r];
        rs += __shfl_xor(rs, 1); rs += __shfl_xor(rs, 2);
        rs += __shfl_xor(rs, 4); rs += __shfl_xor(rs, 8);
        lrow[r] = rs;
    }
#pragma unroll
    for (int r = 0; r < 4; ++r) {
        int row = qs + w * 16 + (l >> 4) * 4 + r;
        float inv = 1.f / lrow[r];
#pragma unroll
        for (int dt = 0; dt < 8; ++dt)
            O[((size_t)(b * S_LEN + row)) * HID + h * DH + dt * 16 + (l & 15)] = f2bf(acc[dt][r] * inv);
    }
}

extern "C" void kernel_launch(void* const* d_in, const int* in_sizes, int n_in,
                              void* d_out, int out_size, void* d_ws, size_t ws_size,
                              hipStream_t stream) {
    (void)in_sizes; (void)n_in; (void)out_size; (void)ws_size;
    const float* hs  = (const float*)d_in[0];
    const float* WAq = (const float*)d_in[1];
    const float* WBq = (const float*)d_in[2];
    const float* WAk = (const float*)d_in[3];
    const float* WBk = (const float*)d_in[4];
    const float* WAv = (const float*)d_in[5];
    const float* WBv = (const float*)d_in[6];
    const float* Wo  = (const float*)d_in[7];
    const float* fc  = (const float*)d_in[8];
    const float* fs  = (const float*)d_in[9];

    char* ws = (char*)d_ws;
    ushort* Xb    = (ushort*)(ws + 0);            // 4096x2048 bf16       16.78 MB
    ushort* WtS   = (ushort*)(ws + 16777216);     // 640x2048 bf16         2.62 MB
    ushort* WtBq  = (ushort*)(ws + 19398656);     // 12288x2048 bf16      50.33 MB
    ushort* WtWo  = (ushort*)(ws + 69730304);     // 2048x2048 bf16        8.39 MB
    float*  Small = (float*) (ws + 78118912);     // 4096x640 f32         10.49 MB
    ushort* BqC   = (ushort*)(ws + 88604672);     // 4096x3072 bf16       25.17 MB
    ushort* qB    = (ushort*)(ws + 113770496);    // (B,H,S,D) bf16       16.78 MB
    ushort* kB    = (ushort*)(ws + 130547712);    // (B,KV,S,D) bf16       8.39 MB
    ushort* vTB   = (ushort*)(ws + 138936320);    // (B,KV,D,S) bf16       8.39 MB
    ushort* OB    = (ushort*)(ws + 147324928);    // 4096x2048 bf16       16.78 MB

    k_cvt_bf16<<<8192, 256, 0, stream>>>(hs, Xb, 2097152);
    k_transpose_w<<<dim3(32, 2),   256, 0, stream>>>(WAq, WtS, 96, 0);
    k_transpose_w<<<dim3(32, 1),   256, 0, stream>>>(WAk, WtS, 16, 96);
    k_transpose_w<<<dim3(32, 1),   256, 0, stream>>>(WAv, WtS, 16, 112);
    k_transpose_w<<<dim3(32, 4),   256, 0, stream>>>(WBk, WtS, 256, 128);
    k_transpose_w<<<dim3(32, 4),   256, 0, stream>>>(WBv, WtS, 256, 384);
    k_transpose_w<<<dim3(32, 192), 256, 0, stream>>>(WBq, WtBq, 12288, 0);
    k_transpose_w<<<dim3(32, 32),  256, 0, stream>>>(Wo, WtWo, 2048, 0);

    k_gemm<float><<<dim3(32, 5), 256, 0, stream>>>(Xb, WtS, Small, 640);
    k_contract_kv<<<4096, 512, 0, stream>>>(Small, fc, fs, kB, vTB);

    for (int c = 0; c < 4; ++c) {
        k_gemm8<<<192, 512, 0, stream>>>(Xb, WtBq + (size_t)c * 3072 * KG, BqC, 3072);
        k_contract_q<<<4096, 256, 0, stream>>>(BqC, Small, fc, fs, qB, c);
    }

    k_attn<<<dim3(32, 32), 256, 0, stream>>>(qB, kB, vTB, OB);

    k_gemm<float><<<dim3(32, 16), 256, 0, stream>>>(OB, WtWo, (float*)d_out, 2048);
}

// Round 6
// 502.938 us; speedup vs baseline: 1.1034x; 1.0685x over previous
//
#include <hip/hip_runtime.h>
#include <hip/hip_bf16.h>

#define S_LEN 2048
#define HID 2048
#define NB 2
#define NH 16
#define NKV 8
#define DH 128
#define RQ 6
#define KG 2048
#define SCALING 0.08838834764831845f

typedef __attribute__((ext_vector_type(8))) short s16x8;
typedef __attribute__((ext_vector_type(4))) float f32x4;

__device__ __forceinline__ float bf2f(ushort u) {
    union { unsigned int i; float f; } v; v.i = ((unsigned int)u) << 16; return v.f;
}
__device__ __forceinline__ ushort f2bf(float f) {
    __hip_bfloat16 h = __float2bfloat16(f);
    return *reinterpret_cast<ushort*>(&h);
}
__device__ __forceinline__ void g2lds16(const void* g, void* l) {
    __builtin_amdgcn_global_load_lds((const __attribute__((address_space(1))) void*)g,
                                     (__attribute__((address_space(3))) void*)l, 16, 0, 0);
}

// ---------------- fp32 -> bf16 convert (vector) ----------------
__global__ void k_cvt_bf16(const float* __restrict__ in, ushort* __restrict__ out, int n4) {
    int i = blockIdx.x * 256 + threadIdx.x;
    if (i >= n4) return;
    float4 v = ((const float4*)in)[i];
    ushort4 o;
    o.x = f2bf(v.x); o.y = f2bf(v.y); o.z = f2bf(v.z); o.w = f2bf(v.w);
    ((ushort4*)out)[i] = o;
}

// ---------------- weight transpose+convert: in [K=2048][Nin] f32 -> out [(rowOff+n)][2048] bf16 ----------------
__global__ void k_transpose_w(const float* __restrict__ in, ushort* __restrict__ out, int Nin, int rowOff) {
    __shared__ ushort tile[64][66];
    int k0 = blockIdx.x * 64, n0 = blockIdx.y * 64;
    int t = threadIdx.x;
#pragma unroll
    for (int i = 0; i < 16; ++i) {
        int f = t + i * 256; int r = f >> 6, c = f & 63;
        int nn = n0 + c;
        float v = (nn < Nin) ? in[(size_t)(k0 + r) * Nin + nn] : 0.f;
        tile[r][c] = f2bf(v);
    }
    __syncthreads();
#pragma unroll
    for (int i = 0; i < 16; ++i) {
        int f = t + i * 256; int nr = f >> 6, kc = f & 63;
        int nn = n0 + nr;
        if (nn < Nin) out[(size_t)(rowOff + nn) * KG + k0 + kc] = tile[kc][nr];
    }
}

// ---------------- generic bf16 GEMM: A[M][2048] @ Bt[N][2048]^T -> C[M][ldc], 128x128 tile ----------------
__device__ __forceinline__ void stc(float* p, float v) { *p = v; }
__device__ __forceinline__ void stc(ushort* p, float v) { *p = f2bf(v); }

template<typename OutT>
__global__ __launch_bounds__(256, 2) void k_gemm(const ushort* __restrict__ A,
                                                 const ushort* __restrict__ Bt,
                                                 OutT* __restrict__ C, int ldc) {
    __shared__ ushort lA[128 * 64];
    __shared__ ushort lB[128 * 64];
    const int tid = threadIdx.x;
    const int l = tid & 63, w = tid >> 6;
    const int gx = gridDim.x;
    int flat = blockIdx.y * gx + blockIdx.x;
    const int nwg = gx * gridDim.y;
    if ((nwg & 7) == 0) {
        int qq = nwg >> 3;
        flat = (flat & 7) * qq + (flat >> 3);
    }
    const int m0 = (flat % gx) * 128, n0 = (flat / gx) * 128;
    const int wm = w >> 1, wn = w & 1;
    f32x4 acc[4][4] = {};
    const int swz = 16 * ((tid & 7) ^ ((tid >> 3) & 7));
    const int rowbase = tid >> 3;

    for (int k0 = 0; k0 < KG; k0 += 64) {
#pragma unroll
        for (int i = 0; i < 4; ++i) {
            int row = rowbase + i * 32;
            const char* srcA = (const char*)A + (((size_t)(m0 + row) * KG + k0) * 2) + swz;
            g2lds16(srcA, (char*)lA + tid * 16 + i * 4096);
            const char* srcB = (const char*)Bt + (((size_t)(n0 + row) * KG + k0) * 2) + swz;
            g2lds16(srcB, (char*)lB + tid * 16 + i * 4096);
        }
        __syncthreads();
#pragma unroll
        for (int kk = 0; kk < 2; ++kk) {
            s16x8 af[4], bfr[4];
            const int kb = kk * 64 + (l >> 4) * 16;
#pragma unroll
            for (int mf = 0; mf < 4; ++mf) {
                int row = wm * 64 + mf * 16 + (l & 15);
                af[mf] = *(const s16x8*)((const char*)lA + row * 128 + (kb ^ ((row & 7) << 4)));
            }
#pragma unroll
            for (int nf = 0; nf < 4; ++nf) {
                int row = wn * 64 + nf * 16 + (l & 15);
                bfr[nf] = *(const s16x8*)((const char*)lB + row * 128 + (kb ^ ((row & 7) << 4)));
            }
#pragma unroll
            for (int mf = 0; mf < 4; ++mf)
#pragma unroll
                for (int nf = 0; nf < 4; ++nf)
                    acc[mf][nf] = __builtin_amdgcn_mfma_f32_16x16x32_bf16(af[mf], bfr[nf], acc[mf][nf], 0, 0, 0);
        }
        __syncthreads();
    }
#pragma unroll
    for (int mf = 0; mf < 4; ++mf)
#pragma unroll
        for (int r = 0; r < 4; ++r) {
            int row = m0 + wm * 64 + mf * 16 + (l >> 4) * 4 + r;
#pragma unroll
            for (int nf = 0; nf < 4; ++nf) {
                int col = n0 + wn * 64 + nf * 16 + (l & 15);
                stc(C + (size_t)row * ldc + col, acc[mf][nf][r]);
            }
        }
}

// ---------------- 256x256 8-phase counted-vmcnt GEMM (BK=64, dbuf, T2+T3+T4+T5) ----------------
// M=4096 fixed (16 m-tiles), n-tiles = gridDim.x/16. Per-CU rate ~1200 TF-equiv (R5 measurement);
// launch with grid % 256 == 0 for full utilization.
__global__ __launch_bounds__(512, 2) void k_gemm8(const ushort* __restrict__ A,
                                                  const ushort* __restrict__ Bt,
                                                  ushort* __restrict__ C, int ldc) {
    __shared__ char sB[131072];
    const int tid = threadIdx.x;
    const int l = tid & 63, wid = tid >> 6;
    const int wr = wid >> 2, wc = wid & 3;

    int flat = blockIdx.x;
    const int nwg = gridDim.x;
    if ((nwg & 7) == 0) {
        int qq = nwg >> 3;
        flat = (flat & 7) * qq + (flat >> 3);
    }
    const int m0 = (flat & 15) * 256;
    const int n0 = (flat >> 4) * 256;

    const int rb = tid >> 3;
    const int swz = 16 * ((tid & 7) ^ (rb & 7));
    const char* pAh[2][2];
    const char* pBh[2][2];
#pragma unroll
    for (int h = 0; h < 2; ++h)
#pragma unroll
        for (int j = 0; j < 2; ++j) {
            pAh[h][j] = (const char*)A + (size_t)(m0 + j * 128 + h * 64 + rb) * (KG * 2) + swz;
            pBh[h][j] = (const char*)Bt + (size_t)(n0 + (j * 2 + (tid >> 8)) * 64 + h * 32 + (rb & 31)) * (KG * 2) + swz;
        }

    f32x4 acc[8][4] = {};
    s16x8 af[4][2], bf[4][2];

    const int arow = (l & 15) * 128;
    const int kxor0 = (0 * 64 + (l >> 4) * 16) ^ ((l & 7) << 4);
    const int kxor1 = (1 * 64 + (l >> 4) * 16) ^ ((l & 7) << 4);

#define STG_A(T, D, H)                                                                     \
    do {                                                                                   \
        g2lds16(pAh[H][0] + (size_t)(T) * 128, sB + (D) * 65536 + (H) * 16384 + tid * 16); \
        g2lds16(pAh[H][1] + (size_t)(T) * 128, sB + (D) * 65536 + (H) * 16384 + 8192 + tid * 16); \
    } while (0)
#define STG_B(T, D, H)                                                                     \
    do {                                                                                   \
        g2lds16(pBh[H][0] + (size_t)(T) * 128, sB + (D) * 65536 + 32768 + (H) * 16384 + tid * 16); \
        g2lds16(pBh[H][1] + (size_t)(T) * 128, sB + (D) * 65536 + 32768 + (H) * 16384 + 8192 + tid * 16); \
    } while (0)
#define RD_A(D, MH)                                                                        \
    do {                                                                                   \
        const char* ab = sB + (D) * 65536 + (MH) * 16384 + wr * 8192;                      \
        _Pragma("unroll") for (int mi = 0; mi < 4; ++mi) {                                 \
            af[mi][0] = *(const s16x8*)(ab + mi * 2048 + arow + kxor0);                    \
            af[mi][1] = *(const s16x8*)(ab + mi * 2048 + arow + kxor1);                    \
        }                                                                                  \
    } while (0)
#define RD_B(D, BH)                                                                        \
    do {                                                                                   \
        const char* bb = sB + (D) * 65536 + 32768 + (BH) * 16384 + wc * 4096;              \
        _Pragma("unroll") for (int ni = 0; ni < 2; ++ni) {                                 \
            bf[(BH) * 2 + ni][0] = *(const s16x8*)(bb + ni * 2048 + arow + kxor0);         \
            bf[(BH) * 2 + ni][1] = *(const s16x8*)(bb + ni * 2048 + arow + kxor1);         \
        }                                                                                  \
    } while (0)
#define QMFMA(MQ, NQ)                                                                      \
    do {                                                                                   \
        __builtin_amdgcn_s_setprio(1);                                                     \
        _Pragma("unroll") for (int mi = 0; mi < 4; ++mi)                                   \
        _Pragma("unroll") for (int ni = 0; ni < 2; ++ni)                                   \
        _Pragma("unroll") for (int k2 = 0; k2 < 2; ++k2)                                   \
            acc[(MQ) * 4 + mi][(NQ) * 2 + ni] = __builtin_amdgcn_mfma_f32_16x16x32_bf16(   \
                af[mi][k2], bf[(NQ) * 2 + ni][k2], acc[(MQ) * 4 + mi][(NQ) * 2 + ni], 0, 0, 0); \
        __builtin_amdgcn_s_setprio(0);                                                     \
    } while (0)
#define BAR()                                   \
    do {                                        \
        asm volatile("" ::: "memory");          \
        __builtin_amdgcn_s_barrier();           \
        asm volatile("" ::: "memory");          \
    } while (0)
#define VM6() asm volatile("s_waitcnt vmcnt(6)" ::: "memory")
#define VM0() asm volatile("s_waitcnt vmcnt(0)" ::: "memory")

    STG_A(0, 0, 0); STG_A(0, 0, 1); STG_B(0, 0, 0); STG_B(0, 0, 1);
    STG_B(1, 1, 0); STG_B(1, 1, 1); STG_A(1, 1, 0);
    VM6();
    BAR();

    for (int i = 0; i < 16; ++i) {
        const bool last = (i == 15);
        const int t1 = 2 * i + 1, t2 = 2 * i + 2, t3 = 2 * i + 3;
        RD_A(0, 0); RD_B(0, 0);
        STG_A(t1, 1, 1);
        BAR(); QMFMA(0, 0); BAR();
        RD_B(0, 1);
        if (!last) STG_A(t2, 0, 0);
        BAR(); QMFMA(0, 1); BAR();
        RD_A(0, 1);
        if (!last) STG_B(t2, 0, 0);
        BAR(); QMFMA(1, 1); BAR();
        if (!last) { STG_B(t2, 0, 1); VM6(); } else { VM0(); }
        BAR(); QMFMA(1, 0); BAR();
        RD_A(1, 0); RD_B(1, 0);
        if (!last) STG_A(t2, 0, 1);
        BAR(); QMFMA(0, 0); BAR();
        RD_B(1, 1);
        if (!last) STG_B(t3, 1, 0);
        BAR(); QMFMA(0, 1); BAR();
        RD_A(1, 1);
        if (!last) STG_B(t3, 1, 1);
        BAR(); QMFMA(1, 1); BAR();
        if (!last) { STG_A(t3, 1, 0); VM6(); }
        BAR(); QMFMA(1, 0); BAR();
    }

#undef STG_A
#undef STG_B
#undef RD_A
#undef RD_B
#undef QMFMA
#undef BAR
#undef VM6
#undef VM0

#pragma unroll
    for (int mf = 0; mf < 8; ++mf)
#pragma unroll
        for (int r = 0; r < 4; ++r) {
            int row = m0 + wr * 128 + mf * 16 + (l >> 4) * 4 + r;
#pragma unroll
            for (int nf = 0; nf < 4; ++nf) {
                int col = n0 + wc * 64 + nf * 16 + (l & 15);
                C[(size_t)row * ldc + col] = f2bf(acc[mf][nf][r]);
            }
        }
}

// ---------------- contract ranks + rope + scale for q ----------------
// bq rows have `pitch` bf16 cols; head hloc's rank-block at col hloc*768. h = hbase + hloc.
__global__ void k_contract_q(const ushort* __restrict__ bq, const float* __restrict__ small,
                             const float* __restrict__ cosT, const float* __restrict__ sinT,
                             ushort* __restrict__ q, int pitch, int hbase) {
    int srow = blockIdx.x;               // 0..4095 == b*2048 + s
    int b = srow >> 11, sl = srow & 2047;
    int t = threadIdx.x;
    int d2 = t & 63;
    int hloc = blockIdx.y * 4 + (t >> 6);
    int h = hbase + hloc;
    const ushort* bqr = bq + (size_t)srow * pitch + hloc * 768;
    const float* af = small + (size_t)srow * 640 + h * RQ;
    float x1 = 0.f, x2 = 0.f;
#pragma unroll
    for (int r = 0; r < RQ; ++r) {
        float a = af[r];
        x1 += a * bf2f(bqr[r * 128 + d2]);
        x2 += a * bf2f(bqr[r * 128 + 64 + d2]);
    }
    float c = cosT[sl * 64 + d2], s = sinT[sl * 64 + d2];
    float q1 = (x1 * c - x2 * s) * SCALING;
    float q2 = (x1 * s + x2 * c) * SCALING;
    size_t o = ((size_t)(b * NH + h) * S_LEN + sl) * DH + d2;
    q[o] = f2bf(q1);
    q[o + 64] = f2bf(q2);
}

// ---------------- contract ranks for k (rope) and v (write v^T) ----------------
__global__ void k_contract_kv(const float* __restrict__ small, const float* __restrict__ cosT,
                              const float* __restrict__ sinT, ushort* __restrict__ kk,
                              ushort* __restrict__ vT) {
    int srow = blockIdx.x;
    int b = srow >> 11, sl = srow & 2047;
    int t = threadIdx.x;                 // 512 threads
    int d2 = t & 63, g = t >> 6;         // g 0..7
    const float* row = small + (size_t)srow * 640;
    float k1 = 0.f, k2 = 0.f, v1 = 0.f, v2 = 0.f;
#pragma unroll
    for (int r = 0; r < 2; ++r) {
        float ak = row[96 + g * 2 + r];
        k1 += ak * row[128 + r * 128 + d2];
        k2 += ak * row[128 + r * 128 + 64 + d2];
        float av = row[112 + g * 2 + r];
        v1 += av * row[384 + r * 128 + d2];
        v2 += av * row[384 + r * 128 + 64 + d2];
    }
    float c = cosT[sl * 64 + d2], s = sinT[sl * 64 + d2];
    float kr1 = k1 * c - k2 * s, kr2 = k1 * s + k2 * c;
    size_t ko = ((size_t)(b * NKV + g) * S_LEN + sl) * DH + d2;
    kk[ko] = f2bf(kr1);
    kk[ko + 64] = f2bf(kr2);
    size_t vo = ((size_t)(b * NKV + g) * DH + d2) * S_LEN + sl;
    vT[vo] = f2bf(v1);
    vT[vo + (size_t)64 * S_LEN] = f2bf(v2);
}

// ---------------- flash attention: 2 heads/block (shared K/V), 8 waves ----------------
// Fixed-shift softmax (scores capped <=50, shift m=50). Waves 0-3 -> head 2g, 4-7 -> head 2g+1.
// Staging/barriers amortized over 2x compute. Wave-uniform mask fast paths: interior tiles
// skip mask math; diagonal tiles skip QK MFMA + exp on fully-masked upper-triangle blocks.
__global__ __launch_bounds__(512, 2) void k_attn(const ushort* __restrict__ q, const ushort* __restrict__ kk,
                                                 const ushort* __restrict__ vT, ushort* __restrict__ O) {
    __shared__ char sK[16384];   // [64 tok][128 d] bf16, swizzled
    __shared__ char sV[16384];   // [128 d][64 tok] bf16, swizzled
    __shared__ char sP[16384];   // per-wave 2KB x 8
    const int qb = 31 - blockIdx.x;   // heavy blocks first
    const int bg = blockIdx.y;        // 0..15 = b*8+g
    const int b = bg >> 3, g = bg & 7;
    const int tid = threadIdx.x, l = tid & 63, w = tid >> 6;
    const int w4 = w & 3;
    const int h = g * 2 + (w >> 2);
    const int qs = qb * 64;
    const int q0 = qs + w4 * 16;

    const ushort* qbase = q + ((size_t)(b * NH + h) * S_LEN) * DH;
    s16x8 qf[4];
    {
        const char* qrow = (const char*)(qbase + (size_t)(q0 + (l & 15)) * DH);
#pragma unroll
        for (int ds = 0; ds < 4; ++ds)
            qf[ds] = *(const s16x8*)(qrow + ds * 64 + (l >> 4) * 16);
    }
    f32x4 acc[8] = {};
    float lrow[4] = {0.f, 0.f, 0.f, 0.f};

    const size_t kgbase = ((size_t)(b * NKV + g) * S_LEN) * DH * 2;
    const size_t vgbase = ((size_t)(b * NKV + g) * DH) * S_LEN * 2;

    const int jt0 = (qs > 1023) ? ((qs - 1023) >> 6) : 0;
    const int ibase = q0 + (l >> 4) * 4;

    for (int jt = jt0; jt <= qb; ++jt) {
        // stage K (64x256B) + V^T (128x128B) with 512 threads, 2 passes each
#pragma unroll
        for (int i = 0; i < 2; ++i) {
            int row = (tid >> 4) + i * 32;
            int colb = (tid & 15) * 16;
            const char* src = (const char*)kk + kgbase + ((size_t)(jt * 64 + row)) * 256 + (colb ^ ((row & 7) << 4));
            g2lds16(src, sK + tid * 16 + i * 8192);
        }
#pragma unroll
        for (int i = 0; i < 2; ++i) {
            int row = (tid >> 3) + i * 64;
            int colb = (tid & 7) * 16;
            const char* src = (const char*)vT + vgbase + (size_t)row * 4096 + (size_t)jt * 128 + (colb ^ ((row & 7) << 4));
            g2lds16(src, sV + tid * 16 + i * 8192);
        }
        __syncthreads();

        const bool diag = (jt == qb);
        const bool wclip = (jt == jt0) && (qs > 1023);

        // QK^T: 16 q-rows x 64 keys per wave (skip fully-masked blocks on diag tile)
        f32x4 sc[4] = {};
#pragma unroll
        for (int ct = 0; ct < 4; ++ct) {
            if (diag && ct > w4) continue;
            f32x4 z = {};
            int row = ct * 16 + (l & 15);
#pragma unroll
            for (int ds = 0; ds < 4; ++ds) {
                int kb = ds * 64 + (l >> 4) * 16;
                s16x8 kf = *(const s16x8*)(sK + row * 256 + (kb ^ ((row & 7) << 4)));
                z = __builtin_amdgcn_mfma_f32_16x16x32_bf16(qf[ds], kf, z, 0, 0, 0);
            }
            sc[ct] = z;
        }
        // softcap + fixed-shift exp: p = exp(50*tanh(x/50)-50) = exp(-100/(exp(2x/50)+1))
        float p[4][4];
        if (!diag && !wclip) {
#pragma unroll
            for (int ct = 0; ct < 4; ++ct)
#pragma unroll
                for (int r = 0; r < 4; ++r) {
                    float e = __expf(sc[ct][r] * 0.04f);
                    float pe = __expf(-100.f / (e + 1.f));
                    p[ct][r] = pe;
                    lrow[r] += pe;
                }
        } else if (diag) {
#pragma unroll
            for (int ct = 0; ct < 4; ++ct) {
                if (ct > w4) {
#pragma unroll
                    for (int r = 0; r < 4; ++r) p[ct][r] = 0.f;
                    continue;
                }
                int j = jt * 64 + ct * 16 + (l & 15);
#pragma unroll
                for (int r = 0; r < 4; ++r) {
                    float e = __expf(sc[ct][r] * 0.04f);
                    float pe = __expf(-100.f / (e + 1.f));
                    pe = (j <= ibase + r) ? pe : 0.f;
                    p[ct][r] = pe;
                    lrow[r] += pe;
                }
            }
        } else {  // window-clipped first tile
#pragma unroll
            for (int ct = 0; ct < 4; ++ct) {
                int j = jt * 64 + ct * 16 + (l & 15);
#pragma unroll
                for (int r = 0; r < 4; ++r) {
                    float e = __expf(sc[ct][r] * 0.04f);
                    float pe = __expf(-100.f / (e + 1.f));
                    pe = (j > ibase + r - 1024) ? pe : 0.f;
                    p[ct][r] = pe;
                    lrow[r] += pe;
                }
            }
        }
        // P -> per-wave LDS (bf16, swizzled)
#pragma unroll
        for (int ct = 0; ct < 4; ++ct) {
            int col = ct * 16 + (l & 15);
#pragma unroll
            for (int r = 0; r < 4; ++r) {
                int row = (l >> 4) * 4 + r;
                *(ushort*)(sP + w * 2048 + row * 128 + ((col * 2) ^ ((row & 7) << 4))) = f2bf(p[ct][r]);
            }
        }
        // PV
#pragma unroll
        for (int s2 = 0; s2 < 2; ++s2) {
            int rowp = l & 15;
            int kb = s2 * 64 + (l >> 4) * 16;
            s16x8 pf = *(const s16x8*)(sP + w * 2048 + rowp * 128 + (kb ^ ((rowp & 7) << 4)));
#pragma unroll
            for (int dt = 0; dt < 8; ++dt) {
                int d = dt * 16 + (l & 15);
                s16x8 vf = *(const s16x8*)(sV + d * 128 + (kb ^ ((d & 7) << 4)));
                acc[dt] = __builtin_amdgcn_mfma_f32_16x16x32_bf16(pf, vf, acc[dt], 0, 0, 0);
            }
        }
        __syncthreads();
    }
#pragma unroll
    for (int r = 0; r < 4; ++r) {
        float rs = lrow[r];
        rs += __shfl_xor(rs, 1); rs += __shfl_xor(rs, 2);
        rs += __shfl_xor(rs, 4); rs += __shfl_xor(rs, 8);
        lrow[r] = rs;
    }
#pragma unroll
    for (int r = 0; r < 4; ++r) {
        int row = qs + w4 * 16 + (l >> 4) * 4 + r;
        float inv = 1.f / lrow[r];
#pragma unroll
        for (int dt = 0; dt < 8; ++dt)
            O[((size_t)(b * S_LEN + row)) * HID + h * DH + dt * 16 + (l & 15)] = f2bf(acc[dt][r] * inv);
    }
}

extern "C" void kernel_launch(void* const* d_in, const int* in_sizes, int n_in,
                              void* d_out, int out_size, void* d_ws, size_t ws_size,
                              hipStream_t stream) {
    (void)in_sizes; (void)n_in; (void)out_size;
    const float* hs  = (const float*)d_in[0];
    const float* WAq = (const float*)d_in[1];
    const float* WBq = (const float*)d_in[2];
    const float* WAk = (const float*)d_in[3];
    const float* WBk = (const float*)d_in[4];
    const float* WAv = (const float*)d_in[5];
    const float* WBv = (const float*)d_in[6];
    const float* Wo  = (const float*)d_in[7];
    const float* fc  = (const float*)d_in[8];
    const float* fs  = (const float*)d_in[9];

    char* ws = (char*)d_ws;
    // fixed-prefix layout
    ushort* Xb    = (ushort*)(ws + 0);            // 4096x2048 bf16
    ushort* WtS   = (ushort*)(ws + 16777216);     // 640x2048 bf16
    ushort* WtBq  = (ushort*)(ws + 19398656);     // 12288x2048 bf16
    ushort* WtWo  = (ushort*)(ws + 69730304);     // 2048x2048 bf16
    float*  Small = (float*) (ws + 78118912);     // 4096x640 f32
    ushort* BqC   = (ushort*)(ws + 88604672);     // chunk: 4096x3072 / full: 4096x12288 bf16

    const bool bigws = (ws_size >= 239599616ull);
    size_t tail = bigws ? 189267968ull : 113770496ull;
    ushort* qB  = (ushort*)(ws + tail);            // (B,H,S,D) bf16   16.78 MB
    ushort* kB  = (ushort*)(ws + tail + 16777216); // (B,KV,S,D) bf16   8.39 MB
    ushort* vTB = (ushort*)(ws + tail + 25165824); // (B,KV,D,S) bf16   8.39 MB
    ushort* OB  = (ushort*)(ws + tail + 33554432); // 4096x2048 bf16   16.78 MB

    k_cvt_bf16<<<8192, 256, 0, stream>>>(hs, Xb, 2097152);
    k_transpose_w<<<dim3(32, 2),   256, 0, stream>>>(WAq, WtS, 96, 0);
    k_transpose_w<<<dim3(32, 1),   256, 0, stream>>>(WAk, WtS, 16, 96);
    k_transpose_w<<<dim3(32, 1),   256, 0, stream>>>(WAv, WtS, 16, 112);
    k_transpose_w<<<dim3(32, 4),   256, 0, stream>>>(WBk, WtS, 256, 128);
    k_transpose_w<<<dim3(32, 4),   256, 0, stream>>>(WBv, WtS, 256, 384);
    k_transpose_w<<<dim3(32, 192), 256, 0, stream>>>(WBq, WtBq, 12288, 0);
    k_transpose_w<<<dim3(32, 32),  256, 0, stream>>>(Wo, WtWo, 2048, 0);

    k_gemm<float><<<dim3(32, 5), 256, 0, stream>>>(Xb, WtS, Small, 640);
    k_contract_kv<<<4096, 512, 0, stream>>>(Small, fc, fs, kB, vTB);

    if (bigws) {
        // single full-N Bq GEMM: 768 blocks = 3 full grid-waves -> 100% CU utilization
        k_gemm8<<<768, 512, 0, stream>>>(Xb, WtBq, BqC, 12288);
        k_contract_q<<<dim3(4096, 4), 256, 0, stream>>>(BqC, Small, fc, fs, qB, 12288, 0);
    } else {
        for (int c = 0; c < 4; ++c) {
            k_gemm8<<<192, 512, 0, stream>>>(Xb, WtBq + (size_t)c * 3072 * KG, BqC, 3072);
            k_contract_q<<<dim3(4096, 1), 256, 0, stream>>>(BqC, Small, fc, fs, qB, 3072, c * 4);
        }
    }

    k_attn<<<dim3(32, 16), 512, 0, stream>>>(qB, kB, vTB, OB);

    k_gemm<float><<<dim3(32, 16), 256, 0, stream>>>(OB, WtWo, (float*)d_out, 2048);
}

// Round 7
// 499.300 us; speedup vs baseline: 1.1114x; 1.0073x over previous
//
#include <hip/hip_runtime.h>
#include <hip/hip_bf16.h>

#define S_LEN 2048
#define HID 2048
#define NB 2
#define NH 16
#define NKV 8
#define DH 128
#define RQ 6
#define KG 2048
#define SCALING 0.08838834764831845f

typedef __attribute__((ext_vector_type(8))) short s16x8;
typedef __attribute__((ext_vector_type(4))) float f32x4;

__device__ __forceinline__ float bf2f(ushort u) {
    union { unsigned int i; float f; } v; v.i = ((unsigned int)u) << 16; return v.f;
}
__device__ __forceinline__ ushort f2bf(float f) {
    __hip_bfloat16 h = __float2bfloat16(f);
    return *reinterpret_cast<ushort*>(&h);
}
__device__ __forceinline__ void g2lds16(const void* g, void* l) {
    __builtin_amdgcn_global_load_lds((const __attribute__((address_space(1))) void*)g,
                                     (__attribute__((address_space(3))) void*)l, 16, 0, 0);
}

// ---------------- fp32 -> bf16 convert (vector) ----------------
__global__ void k_cvt_bf16(const float* __restrict__ in, ushort* __restrict__ out, int n4) {
    int i = blockIdx.x * 256 + threadIdx.x;
    if (i >= n4) return;
    float4 v = ((const float4*)in)[i];
    ushort4 o;
    o.x = f2bf(v.x); o.y = f2bf(v.y); o.z = f2bf(v.z); o.w = f2bf(v.w);
    ((ushort4*)out)[i] = o;
}

// ---------------- weight transpose+convert: in [K=2048][Nin] f32 -> out [(rowOff+n)][2048] bf16 ----------------
__global__ void k_transpose_w(const float* __restrict__ in, ushort* __restrict__ out, int Nin, int rowOff) {
    __shared__ ushort tile[64][66];
    int k0 = blockIdx.x * 64, n0 = blockIdx.y * 64;
    int t = threadIdx.x;
#pragma unroll
    for (int i = 0; i < 16; ++i) {
        int f = t + i * 256; int r = f >> 6, c = f & 63;
        int nn = n0 + c;
        float v = (nn < Nin) ? in[(size_t)(k0 + r) * Nin + nn] : 0.f;
        tile[r][c] = f2bf(v);
    }
    __syncthreads();
#pragma unroll
    for (int i = 0; i < 16; ++i) {
        int f = t + i * 256; int nr = f >> 6, kc = f & 63;
        int nn = n0 + nr;
        if (nn < Nin) out[(size_t)(rowOff + nn) * KG + k0 + kc] = tile[kc][nr];
    }
}

// ---------------- generic bf16 GEMM: A[M][2048] @ Bt[N][2048]^T -> C[M][ldc], 128x128 tile ----------------
__device__ __forceinline__ void stc(float* p, float v) { *p = v; }
__device__ __forceinline__ void stc(ushort* p, float v) { *p = f2bf(v); }

template<typename OutT>
__global__ __launch_bounds__(256, 2) void k_gemm(const ushort* __restrict__ A,
                                                 const ushort* __restrict__ Bt,
                                                 OutT* __restrict__ C, int ldc) {
    __shared__ ushort lA[128 * 64];
    __shared__ ushort lB[128 * 64];
    const int tid = threadIdx.x;
    const int l = tid & 63, w = tid >> 6;
    const int gx = gridDim.x;
    int flat = blockIdx.y * gx + blockIdx.x;
    const int nwg = gx * gridDim.y;
    if ((nwg & 7) == 0) {
        int qq = nwg >> 3;
        flat = (flat & 7) * qq + (flat >> 3);
    }
    const int m0 = (flat % gx) * 128, n0 = (flat / gx) * 128;
    const int wm = w >> 1, wn = w & 1;
    f32x4 acc[4][4] = {};
    const int swz = 16 * ((tid & 7) ^ ((tid >> 3) & 7));
    const int rowbase = tid >> 3;

    for (int k0 = 0; k0 < KG; k0 += 64) {
#pragma unroll
        for (int i = 0; i < 4; ++i) {
            int row = rowbase + i * 32;
            const char* srcA = (const char*)A + (((size_t)(m0 + row) * KG + k0) * 2) + swz;
            g2lds16(srcA, (char*)lA + tid * 16 + i * 4096);
            const char* srcB = (const char*)Bt + (((size_t)(n0 + row) * KG + k0) * 2) + swz;
            g2lds16(srcB, (char*)lB + tid * 16 + i * 4096);
        }
        __syncthreads();
#pragma unroll
        for (int kk = 0; kk < 2; ++kk) {
            s16x8 af[4], bfr[4];
            const int kb = kk * 64 + (l >> 4) * 16;
#pragma unroll
            for (int mf = 0; mf < 4; ++mf) {
                int row = wm * 64 + mf * 16 + (l & 15);
                af[mf] = *(const s16x8*)((const char*)lA + row * 128 + (kb ^ ((row & 7) << 4)));
            }
#pragma unroll
            for (int nf = 0; nf < 4; ++nf) {
                int row = wn * 64 + nf * 16 + (l & 15);
                bfr[nf] = *(const s16x8*)((const char*)lB + row * 128 + (kb ^ ((row & 7) << 4)));
            }
#pragma unroll
            for (int mf = 0; mf < 4; ++mf)
#pragma unroll
                for (int nf = 0; nf < 4; ++nf)
                    acc[mf][nf] = __builtin_amdgcn_mfma_f32_16x16x32_bf16(af[mf], bfr[nf], acc[mf][nf], 0, 0, 0);
        }
        __syncthreads();
    }
#pragma unroll
    for (int mf = 0; mf < 4; ++mf)
#pragma unroll
        for (int r = 0; r < 4; ++r) {
            int row = m0 + wm * 64 + mf * 16 + (l >> 4) * 4 + r;
#pragma unroll
            for (int nf = 0; nf < 4; ++nf) {
                int col = n0 + wn * 64 + nf * 16 + (l & 15);
                stc(C + (size_t)row * ldc + col, acc[mf][nf][r]);
            }
        }
}

// ---------------- 256x256 8-phase counted-vmcnt GEMM (BK=64, dbuf, T2+T3+T4+T5) ----------------
__global__ __launch_bounds__(512, 2) void k_gemm8(const ushort* __restrict__ A,
                                                  const ushort* __restrict__ Bt,
                                                  ushort* __restrict__ C, int ldc) {
    __shared__ char sB[131072];
    const int tid = threadIdx.x;
    const int l = tid & 63, wid = tid >> 6;
    const int wr = wid >> 2, wc = wid & 3;

    int flat = blockIdx.x;
    const int nwg = gridDim.x;
    if ((nwg & 7) == 0) {
        int qq = nwg >> 3;
        flat = (flat & 7) * qq + (flat >> 3);
    }
    const int m0 = (flat & 15) * 256;
    const int n0 = (flat >> 4) * 256;

    const int rb = tid >> 3;
    const int swz = 16 * ((tid & 7) ^ (rb & 7));
    const char* pAh[2][2];
    const char* pBh[2][2];
#pragma unroll
    for (int h = 0; h < 2; ++h)
#pragma unroll
        for (int j = 0; j < 2; ++j) {
            pAh[h][j] = (const char*)A + (size_t)(m0 + j * 128 + h * 64 + rb) * (KG * 2) + swz;
            pBh[h][j] = (const char*)Bt + (size_t)(n0 + (j * 2 + (tid >> 8)) * 64 + h * 32 + (rb & 31)) * (KG * 2) + swz;
        }

    f32x4 acc[8][4] = {};
    s16x8 af[4][2], bf[4][2];

    const int arow = (l & 15) * 128;
    const int kxor0 = (0 * 64 + (l >> 4) * 16) ^ ((l & 7) << 4);
    const int kxor1 = (1 * 64 + (l >> 4) * 16) ^ ((l & 7) << 4);

#define STG_A(T, D, H)                                                                     \
    do {                                                                                   \
        g2lds16(pAh[H][0] + (size_t)(T) * 128, sB + (D) * 65536 + (H) * 16384 + tid * 16); \
        g2lds16(pAh[H][1] + (size_t)(T) * 128, sB + (D) * 65536 + (H) * 16384 + 8192 + tid * 16); \
    } while (0)
#define STG_B(T, D, H)                                                                     \
    do {                                                                                   \
        g2lds16(pBh[H][0] + (size_t)(T) * 128, sB + (D) * 65536 + 32768 + (H) * 16384 + tid * 16); \
        g2lds16(pBh[H][1] + (size_t)(T) * 128, sB + (D) * 65536 + 32768 + (H) * 16384 + 8192 + tid * 16); \
    } while (0)
#define RD_A(D, MH)                                                                        \
    do {                                                                                   \
        const char* ab = sB + (D) * 65536 + (MH) * 16384 + wr * 8192;                      \
        _Pragma("unroll") for (int mi = 0; mi < 4; ++mi) {                                 \
            af[mi][0] = *(const s16x8*)(ab + mi * 2048 + arow + kxor0);                    \
            af[mi][1] = *(const s16x8*)(ab + mi * 2048 + arow + kxor1);                    \
        }                                                                                  \
    } while (0)
#define RD_B(D, BH)                                                                        \
    do {                                                                                   \
        const char* bb = sB + (D) * 65536 + 32768 + (BH) * 16384 + wc * 4096;              \
        _Pragma("unroll") for (int ni = 0; ni < 2; ++ni) {                                 \
            bf[(BH) * 2 + ni][0] = *(const s16x8*)(bb + ni * 2048 + arow + kxor0);         \
            bf[(BH) * 2 + ni][1] = *(const s16x8*)(bb + ni * 2048 + arow + kxor1);         \
        }                                                                                  \
    } while (0)
#define QMFMA(MQ, NQ)                                                                      \
    do {                                                                                   \
        __builtin_amdgcn_s_setprio(1);                                                     \
        _Pragma("unroll") for (int mi = 0; mi < 4; ++mi)                                   \
        _Pragma("unroll") for (int ni = 0; ni < 2; ++ni)                                   \
        _Pragma("unroll") for (int k2 = 0; k2 < 2; ++k2)                                   \
            acc[(MQ) * 4 + mi][(NQ) * 2 + ni] = __builtin_amdgcn_mfma_f32_16x16x32_bf16(   \
                af[mi][k2], bf[(NQ) * 2 + ni][k2], acc[(MQ) * 4 + mi][(NQ) * 2 + ni], 0, 0, 0); \
        __builtin_amdgcn_s_setprio(0);                                                     \
    } while (0)
#define BAR()                                   \
    do {                                        \
        asm volatile("" ::: "memory");          \
        __builtin_amdgcn_s_barrier();           \
        asm volatile("" ::: "memory");          \
    } while (0)
#define VM6() asm volatile("s_waitcnt vmcnt(6)" ::: "memory")
#define VM0() asm volatile("s_waitcnt vmcnt(0)" ::: "memory")

    STG_A(0, 0, 0); STG_A(0, 0, 1); STG_B(0, 0, 0); STG_B(0, 0, 1);
    STG_B(1, 1, 0); STG_B(1, 1, 1); STG_A(1, 1, 0);
    VM6();
    BAR();

    for (int i = 0; i < 16; ++i) {
        const bool last = (i == 15);
        const int t1 = 2 * i + 1, t2 = 2 * i + 2, t3 = 2 * i + 3;
        RD_A(0, 0); RD_B(0, 0);
        STG_A(t1, 1, 1);
        BAR(); QMFMA(0, 0); BAR();
        RD_B(0, 1);
        if (!last) STG_A(t2, 0, 0);
        BAR(); QMFMA(0, 1); BAR();
        RD_A(0, 1);
        if (!last) STG_B(t2, 0, 0);
        BAR(); QMFMA(1, 1); BAR();
        if (!last) { STG_B(t2, 0, 1); VM6(); } else { VM0(); }
        BAR(); QMFMA(1, 0); BAR();
        RD_A(1, 0); RD_B(1, 0);
        if (!last) STG_A(t2, 0, 1);
        BAR(); QMFMA(0, 0); BAR();
        RD_B(1, 1);
        if (!last) STG_B(t3, 1, 0);
        BAR(); QMFMA(0, 1); BAR();
        RD_A(1, 1);
        if (!last) STG_B(t3, 1, 1);
        BAR(); QMFMA(1, 1); BAR();
        if (!last) { STG_A(t3, 1, 0); VM6(); }
        BAR(); QMFMA(1, 0); BAR();
    }

#undef STG_A
#undef STG_B
#undef RD_A
#undef RD_B
#undef QMFMA

#pragma unroll
    for (int mf = 0; mf < 8; ++mf)
#pragma unroll
        for (int r = 0; r < 4; ++r) {
            int row = m0 + wr * 128 + mf * 16 + (l >> 4) * 4 + r;
#pragma unroll
            for (int nf = 0; nf < 4; ++nf) {
                int col = n0 + wc * 64 + nf * 16 + (l & 15);
                C[(size_t)row * ldc + col] = f2bf(acc[mf][nf][r]);
            }
        }
#undef BAR
#undef VM6
#undef VM0
}

// ---------------- 128x256 8-phase counted-vmcnt GEMM (BK=64, dbuf), f32 out ----------------
// M=4096 (32 m-tiles), n-tiles = gridDim.x/32. 512 thr, 8 waves 2Mx4N, per-wave 64x64.
// LDS 96KB: dbuf d at d*49152; A 16KB as halves H=[wr2][32 rows][128B]; B 32KB at +16384
// as halves H=[wc4][32 rows][128B]. 6 loads/K-tile/thread; vmcnt(5) at ph4/ph8
// (FIFO: 11 outstanding, oldest 6 = previous tile complete). Half-granular WAR staggering
// mirrors k_gemm8 (each half written one phase after its last read).
__global__ __launch_bounds__(512, 2) void k_gemm8h(const ushort* __restrict__ A,
                                                   const ushort* __restrict__ Bt,
                                                   float* __restrict__ C, int ldc) {
    __shared__ char sB[98304];
    const int tid = threadIdx.x;
    const int l = tid & 63, wid = tid >> 6;
    const int wr = wid >> 2, wc = wid & 3;

    int flat = blockIdx.x;
    const int nwg = gridDim.x;
    if ((nwg & 7) == 0) {
        int qq = nwg >> 3;
        flat = (flat & 7) * qq + (flat >> 3);
    }
    const int m0 = (flat & 31) * 128;
    const int n0 = (flat >> 5) * 256;

    const int rb = tid >> 3;
    const int swz = 16 * ((tid & 7) ^ (rb & 7));
    const char* pA_[2];
    const char* pB_[2][2];
#pragma unroll
    for (int h = 0; h < 2; ++h) {
        pA_[h] = (const char*)A + (size_t)(m0 + (tid >> 8) * 64 + h * 32 + (rb & 31)) * (KG * 2) + swz;
#pragma unroll
        for (int j = 0; j < 2; ++j)
            pB_[h][j] = (const char*)Bt + (size_t)(n0 + (j * 2 + (tid >> 8)) * 64 + h * 32 + (rb & 31)) * (KG * 2) + swz;
    }

    f32x4 acc[4][4] = {};
    s16x8 af[2][2], bf[4][2];

    const int arow = (l & 15) * 128;
    const int kxor0 = ((l >> 4) * 16) ^ ((l & 7) << 4);
    const int kxor1 = (64 + (l >> 4) * 16) ^ ((l & 7) << 4);

#define STG_AH(T, D, H)                                                                    \
    g2lds16(pA_[H] + (size_t)(T) * 128, sB + (D) * 49152 + (H) * 8192 + tid * 16)
#define STG_BH(T, D, H)                                                                    \
    do {                                                                                   \
        g2lds16(pB_[H][0] + (size_t)(T) * 128, sB + (D) * 49152 + 16384 + (H) * 16384 + tid * 16); \
        g2lds16(pB_[H][1] + (size_t)(T) * 128, sB + (D) * 49152 + 16384 + (H) * 16384 + 8192 + tid * 16); \
    } while (0)
#define RD_AH(D, MH)                                                                       \
    do {                                                                                   \
        const char* ab = sB + (D) * 49152 + (MH) * 8192 + wr * 4096;                       \
        _Pragma("unroll") for (int mi = 0; mi < 2; ++mi) {                                 \
            af[mi][0] = *(const s16x8*)(ab + mi * 2048 + arow + kxor0);                    \
            af[mi][1] = *(const s16x8*)(ab + mi * 2048 + arow + kxor1);                    \
        }                                                                                  \
    } while (0)
#define RD_BH(D, BH)                                                                       \
    do {                                                                                   \
        const char* bb = sB + (D) * 49152 + 16384 + (BH) * 16384 + wc * 4096;              \
        _Pragma("unroll") for (int ni = 0; ni < 2; ++ni) {                                 \
            bf[(BH) * 2 + ni][0] = *(const s16x8*)(bb + ni * 2048 + arow + kxor0);         \
            bf[(BH) * 2 + ni][1] = *(const s16x8*)(bb + ni * 2048 + arow + kxor1);         \
        }                                                                                  \
    } while (0)
#define QMFMAH(MQ, NQ)                                                                     \
    do {                                                                                   \
        __builtin_amdgcn_s_setprio(1);                                                     \
        _Pragma("unroll") for (int mi = 0; mi < 2; ++mi)                                   \
        _Pragma("unroll") for (int ni = 0; ni < 2; ++ni)                                   \
        _Pragma("unroll") for (int k2 = 0; k2 < 2; ++k2)                                   \
            acc[(MQ) * 2 + mi][(NQ) * 2 + ni] = __builtin_amdgcn_mfma_f32_16x16x32_bf16(   \
                af[mi][k2], bf[(NQ) * 2 + ni][k2], acc[(MQ) * 2 + mi][(NQ) * 2 + ni], 0, 0, 0); \
        __builtin_amdgcn_s_setprio(0);                                                     \
    } while (0)
#define BAR()                                   \
    do {                                        \
        asm volatile("" ::: "memory");          \
        __builtin_amdgcn_s_barrier();           \
        asm volatile("" ::: "memory");          \
    } while (0)
#define VM5() asm volatile("s_waitcnt vmcnt(5)" ::: "memory")
#define VM0() asm volatile("s_waitcnt vmcnt(0)" ::: "memory")

    // prologue: T0 full (6) -> d0; T1 {B0,B1,A0} (5) -> d1; T1.A1 staged at iter0 ph1
    STG_AH(0, 0, 0); STG_AH(0, 0, 1); STG_BH(0, 0, 0); STG_BH(0, 0, 1);
    STG_BH(1, 1, 0); STG_BH(1, 1, 1); STG_AH(1, 1, 0);
    VM5();
    BAR();

    for (int i = 0; i < 16; ++i) {
        const bool last = (i == 15);
        const int t1 = 2 * i + 1, t2 = 2 * i + 2, t3 = 2 * i + 3;
        RD_AH(0, 0); RD_BH(0, 0);
        STG_AH(t1, 1, 1);
        BAR(); QMFMAH(0, 0); BAR();
        RD_BH(0, 1);
        if (!last) STG_AH(t2, 0, 0);
        BAR(); QMFMAH(0, 1); BAR();
        RD_AH(0, 1);
        if (!last) STG_BH(t2, 0, 0);
        BAR(); QMFMAH(1, 1); BAR();
        if (!last) { STG_BH(t2, 0, 1); VM5(); } else { VM0(); }
        BAR(); QMFMAH(1, 0); BAR();
        RD_AH(1, 0); RD_BH(1, 0);
        if (!last) STG_AH(t2, 0, 1);
        BAR(); QMFMAH(0, 0); BAR();
        RD_BH(1, 1);
        if (!last) STG_BH(t3, 1, 0);
        BAR(); QMFMAH(0, 1); BAR();
        RD_AH(1, 1);
        if (!last) STG_BH(t3, 1, 1);
        BAR(); QMFMAH(1, 1); BAR();
        if (!last) { STG_AH(t3, 1, 0); VM5(); }
        BAR(); QMFMAH(1, 0); BAR();
    }

#undef STG_AH
#undef STG_BH
#undef RD_AH
#undef RD_BH
#undef QMFMAH
#undef BAR
#undef VM5
#undef VM0

#pragma unroll
    for (int a = 0; a < 4; ++a)
#pragma unroll
        for (int r = 0; r < 4; ++r) {
            int row = m0 + wr * 64 + a * 16 + (l >> 4) * 4 + r;
#pragma unroll
            for (int b2 = 0; b2 < 4; ++b2) {
                int col = n0 + wc * 64 + b2 * 16 + (l & 15);
                C[(size_t)row * ldc + col] = acc[a][b2][r];
            }
        }
}

// ---------------- contract ranks + rope + scale for q ----------------
__global__ void k_contract_q(const ushort* __restrict__ bq, const float* __restrict__ small,
                             const float* __restrict__ cosT, const float* __restrict__ sinT,
                             ushort* __restrict__ q, int pitch, int hbase) {
    int srow = blockIdx.x;               // 0..4095 == b*2048 + s
    int b = srow >> 11, sl = srow & 2047;
    int t = threadIdx.x;
    int d2 = t & 63;
    int hloc = blockIdx.y * 4 + (t >> 6);
    int h = hbase + hloc;
    const ushort* bqr = bq + (size_t)srow * pitch + hloc * 768;
    const float* af = small + (size_t)srow * 640 + h * RQ;
    float x1 = 0.f, x2 = 0.f;
#pragma unroll
    for (int r = 0; r < RQ; ++r) {
        float a = af[r];
        x1 += a * bf2f(bqr[r * 128 + d2]);
        x2 += a * bf2f(bqr[r * 128 + 64 + d2]);
    }
    float c = cosT[sl * 64 + d2], s = sinT[sl * 64 + d2];
    float q1 = (x1 * c - x2 * s) * SCALING;
    float q2 = (x1 * s + x2 * c) * SCALING;
    size_t o = ((size_t)(b * NH + h) * S_LEN + sl) * DH + d2;
    q[o] = f2bf(q1);
    q[o + 64] = f2bf(q2);
}

// ---------------- contract ranks for k (rope) and v (write v^T) ----------------
__global__ void k_contract_kv(const float* __restrict__ small, const float* __restrict__ cosT,
                              const float* __restrict__ sinT, ushort* __restrict__ kk,
                              ushort* __restrict__ vT) {
    int srow = blockIdx.x;
    int b = srow >> 11, sl = srow & 2047;
    int t = threadIdx.x;                 // 512 threads
    int d2 = t & 63, g = t >> 6;         // g 0..7
    const float* row = small + (size_t)srow * 640;
    float k1 = 0.f, k2 = 0.f, v1 = 0.f, v2 = 0.f;
#pragma unroll
    for (int r = 0; r < 2; ++r) {
        float ak = row[96 + g * 2 + r];
        k1 += ak * row[128 + r * 128 + d2];
        k2 += ak * row[128 + r * 128 + 64 + d2];
        float av = row[112 + g * 2 + r];
        v1 += av * row[384 + r * 128 + d2];
        v2 += av * row[384 + r * 128 + 64 + d2];
    }
    float c = cosT[sl * 64 + d2], s = sinT[sl * 64 + d2];
    float kr1 = k1 * c - k2 * s, kr2 = k1 * s + k2 * c;
    size_t ko = ((size_t)(b * NKV + g) * S_LEN + sl) * DH + d2;
    kk[ko] = f2bf(kr1);
    kk[ko + 64] = f2bf(kr2);
    size_t vo = ((size_t)(b * NKV + g) * DH + d2) * S_LEN + sl;
    vT[vo] = f2bf(v1);
    vT[vo + (size_t)64 * S_LEN] = f2bf(v2);
}

// ---------------- flash attention: 2 heads/block (shared K/V), 8 waves ----------------
__global__ __launch_bounds__(512, 2) void k_attn(const ushort* __restrict__ q, const ushort* __restrict__ kk,
                                                 const ushort* __restrict__ vT, ushort* __restrict__ O) {
    __shared__ char sK[16384];   // [64 tok][128 d] bf16, swizzled
    __shared__ char sV[16384];   // [128 d][64 tok] bf16, swizzled
    __shared__ char sP[16384];   // per-wave 2KB x 8
    const int qb = 31 - blockIdx.x;   // heavy blocks first
    const int bg = blockIdx.y;        // 0..15 = b*8+g
    const int b = bg >> 3, g = bg & 7;
    const int tid = threadIdx.x, l = tid & 63, w = tid >> 6;
    const int w4 = w & 3;
    const int h = g * 2 + (w >> 2);
    const int qs = qb * 64;
    const int q0 = qs + w4 * 16;

    const ushort* qbase = q + ((size_t)(b * NH + h) * S_LEN) * DH;
    s16x8 qf[4];
    {
        const char* qrow = (const char*)(qbase + (size_t)(q0 + (l & 15)) * DH);
#pragma unroll
        for (int ds = 0; ds < 4; ++ds)
            qf[ds] = *(const s16x8*)(qrow + ds * 64 + (l >> 4) * 16);
    }
    f32x4 acc[8] = {};
    float lrow[4] = {0.f, 0.f, 0.f, 0.f};

    const size_t kgbase = ((size_t)(b * NKV + g) * S_LEN) * DH * 2;
    const size_t vgbase = ((size_t)(b * NKV + g) * DH) * S_LEN * 2;

    const int jt0 = (qs > 1023) ? ((qs - 1023) >> 6) : 0;
    const int ibase = q0 + (l >> 4) * 4;

    for (int jt = jt0; jt <= qb; ++jt) {
#pragma unroll
        for (int i = 0; i < 2; ++i) {
            int row = (tid >> 4) + i * 32;
            int colb = (tid & 15) * 16;
            const char* src = (const char*)kk + kgbase + ((size_t)(jt * 64 + row)) * 256 + (colb ^ ((row & 7) << 4));
            g2lds16(src, sK + tid * 16 + i * 8192);
        }
#pragma unroll
        for (int i = 0; i < 2; ++i) {
            int row = (tid >> 3) + i * 64;
            int colb = (tid & 7) * 16;
            const char* src = (const char*)vT + vgbase + (size_t)row * 4096 + (size_t)jt * 128 + (colb ^ ((row & 7) << 4));
            g2lds16(src, sV + tid * 16 + i * 8192);
        }
        __syncthreads();

        const bool diag = (jt == qb);
        const bool wclip = (jt == jt0) && (qs > 1023);

        f32x4 sc[4] = {};
#pragma unroll
        for (int ct = 0; ct < 4; ++ct) {
            if (diag && ct > w4) continue;
            f32x4 z = {};
            int row = ct * 16 + (l & 15);
#pragma unroll
            for (int ds = 0; ds < 4; ++ds) {
                int kb = ds * 64 + (l >> 4) * 16;
                s16x8 kf = *(const s16x8*)(sK + row * 256 + (kb ^ ((row & 7) << 4)));
                z = __builtin_amdgcn_mfma_f32_16x16x32_bf16(qf[ds], kf, z, 0, 0, 0);
            }
            sc[ct] = z;
        }
        float p[4][4];
        if (!diag && !wclip) {
#pragma unroll
            for (int ct = 0; ct < 4; ++ct)
#pragma unroll
                for (int r = 0; r < 4; ++r) {
                    float e = __expf(sc[ct][r] * 0.04f);
                    float pe = __expf(-100.f / (e + 1.f));
                    p[ct][r] = pe;
                    lrow[r] += pe;
                }
        } else if (diag) {
#pragma unroll
            for (int ct = 0; ct < 4; ++ct) {
                if (ct > w4) {
#pragma unroll
                    for (int r = 0; r < 4; ++r) p[ct][r] = 0.f;
                    continue;
                }
                int j = jt * 64 + ct * 16 + (l & 15);
#pragma unroll
                for (int r = 0; r < 4; ++r) {
                    float e = __expf(sc[ct][r] * 0.04f);
                    float pe = __expf(-100.f / (e + 1.f));
                    pe = (j <= ibase + r) ? pe : 0.f;
                    p[ct][r] = pe;
                    lrow[r] += pe;
                }
            }
        } else {
#pragma unroll
            for (int ct = 0; ct < 4; ++ct) {
                int j = jt * 64 + ct * 16 + (l & 15);
#pragma unroll
                for (int r = 0; r < 4; ++r) {
                    float e = __expf(sc[ct][r] * 0.04f);
                    float pe = __expf(-100.f / (e + 1.f));
                    pe = (j > ibase + r - 1024) ? pe : 0.f;
                    p[ct][r] = pe;
                    lrow[r] += pe;
                }
            }
        }
#pragma unroll
        for (int ct = 0; ct < 4; ++ct) {
            int col = ct * 16 + (l & 15);
#pragma unroll
            for (int r = 0; r < 4; ++r) {
                int row = (l >> 4) * 4 + r;
                *(ushort*)(sP + w * 2048 + row * 128 + ((col * 2) ^ ((row & 7) << 4))) = f2bf(p[ct][r]);
            }
        }
#pragma unroll
        for (int s2 = 0; s2 < 2; ++s2) {
            int rowp = l & 15;
            int kb = s2 * 64 + (l >> 4) * 16;
            s16x8 pf = *(const s16x8*)(sP + w * 2048 + rowp * 128 + (kb ^ ((rowp & 7) << 4)));
#pragma unroll
            for (int dt = 0; dt < 8; ++dt) {
                int d = dt * 16 + (l & 15);
                s16x8 vf = *(const s16x8*)(sV + d * 128 + (kb ^ ((d & 7) << 4)));
                acc[dt] = __builtin_amdgcn_mfma_f32_16x16x32_bf16(pf, vf, acc[dt], 0, 0, 0);
            }
        }
        __syncthreads();
    }
#pragma unroll
    for (int r = 0; r < 4; ++r) {
        float rs = lrow[r];
        rs += __shfl_xor(rs, 1); rs += __shfl_xor(rs, 2);
        rs += __shfl_xor(rs, 4); rs += __shfl_xor(rs, 8);
        lrow[r] = rs;
    }
#pragma unroll
    for (int r = 0; r < 4; ++r) {
        int row = qs + w4 * 16 + (l >> 4) * 4 + r;
        float inv = 1.f / lrow[r];
#pragma unroll
        for (int dt = 0; dt < 8; ++dt)
            O[((size_t)(b * S_LEN + row)) * HID + h * DH + dt * 16 + (l & 15)] = f2bf(acc[dt][r] * inv);
    }
}

extern "C" void kernel_launch(void* const* d_in, const int* in_sizes, int n_in,
                              void* d_out, int out_size, void* d_ws, size_t ws_size,
                              hipStream_t stream) {
    (void)in_sizes; (void)n_in; (void)out_size;
    const float* hs  = (const float*)d_in[0];
    const float* WAq = (const float*)d_in[1];
    const float* WBq = (const float*)d_in[2];
    const float* WAk = (const float*)d_in[3];
    const float* WBk = (const float*)d_in[4];
    const float* WAv = (const float*)d_in[5];
    const float* WBv = (const float*)d_in[6];
    const float* Wo  = (const float*)d_in[7];
    const float* fc  = (const float*)d_in[8];
    const float* fs  = (const float*)d_in[9];

    char* ws = (char*)d_ws;
    ushort* Xb    = (ushort*)(ws + 0);            // 4096x2048 bf16
    ushort* WtS   = (ushort*)(ws + 16777216);     // 640x2048 bf16
    ushort* WtBq  = (ushort*)(ws + 19398656);     // 12288x2048 bf16
    ushort* WtWo  = (ushort*)(ws + 69730304);     // 2048x2048 bf16
    float*  Small = (float*) (ws + 78118912);     // 4096x640 f32
    ushort* BqC   = (ushort*)(ws + 88604672);     // chunk: 4096x3072 / full: 4096x12288 bf16

    const bool bigws = (ws_size >= 239599616ull);
    size_t tail = bigws ? 189267968ull : 113770496ull;
    ushort* qB  = (ushort*)(ws + tail);            // (B,H,S,D) bf16   16.78 MB
    ushort* kB  = (ushort*)(ws + tail + 16777216); // (B,KV,S,D) bf16   8.39 MB
    ushort* vTB = (ushort*)(ws + tail + 25165824); // (B,KV,D,S) bf16   8.39 MB
    ushort* OB  = (ushort*)(ws + tail + 33554432); // 4096x2048 bf16   16.78 MB

    k_cvt_bf16<<<8192, 256, 0, stream>>>(hs, Xb, 2097152);
    k_transpose_w<<<dim3(32, 2),   256, 0, stream>>>(WAq, WtS, 96, 0);
    k_transpose_w<<<dim3(32, 1),   256, 0, stream>>>(WAk, WtS, 16, 96);
    k_transpose_w<<<dim3(32, 1),   256, 0, stream>>>(WAv, WtS, 16, 112);
    k_transpose_w<<<dim3(32, 4),   256, 0, stream>>>(WBk, WtS, 256, 128);
    k_transpose_w<<<dim3(32, 4),   256, 0, stream>>>(WBv, WtS, 256, 384);
    k_transpose_w<<<dim3(32, 192), 256, 0, stream>>>(WBq, WtBq, 12288, 0);
    k_transpose_w<<<dim3(32, 32),  256, 0, stream>>>(Wo, WtWo, 2048, 0);

    k_gemm<float><<<dim3(32, 5), 256, 0, stream>>>(Xb, WtS, Small, 640);
    k_contract_kv<<<4096, 512, 0, stream>>>(Small, fc, fs, kB, vTB);

    if (bigws) {
        k_gemm8<<<768, 512, 0, stream>>>(Xb, WtBq, BqC, 12288);
        k_contract_q<<<dim3(4096, 4), 256, 0, stream>>>(BqC, Small, fc, fs, qB, 12288, 0);
    } else {
        for (int c = 0; c < 4; ++c) {
            k_gemm8<<<192, 512, 0, stream>>>(Xb, WtBq + (size_t)c * 3072 * KG, BqC, 3072);
            k_contract_q<<<dim3(4096, 1), 256, 0, stream>>>(BqC, Small, fc, fs, qB, 3072, c * 4);
        }
    }

    k_attn<<<dim3(32, 16), 512, 0, stream>>>(qB, kB, vTB, OB);

    // Wo GEMM: 128x256 8-phase, 32 m-tiles x 8 n-tiles = 256 blocks = 1/CU (full util)
    k_gemm8h<<<256, 512, 0, stream>>>(OB, WtWo, (float*)d_out, 2048);
}